// Round 1
// baseline (7922.321 us; speedup 1.0000x reference)
//
#include <hip/hip_runtime.h>
#include <math.h>

#define BB 128
#define TT 128
#define VV 64
#define DD 32
#define NQ 5

__device__ __forceinline__ float sigm(float x){ return 1.0f/(1.0f+__expf(-x)); }
__device__ __forceinline__ float tanhfast(float x){ return 2.0f/(1.0f+__expf(-2.0f*x)) - 1.0f; }

// ---------------- precompute kernels ----------------

// var_vector (64x5) and normalized gvec (64x8)
__global__ __launch_bounds__(64)
void k_mlp(const float* __restrict__ Pplm,
           const float* __restrict__ Ws1, const float* __restrict__ bs1,
           const float* __restrict__ Ws2, const float* __restrict__ bs2,
           const float* __restrict__ Wg1, const float* __restrict__ bg1,
           const float* __restrict__ Wg2, const float* __restrict__ bg2,
           float* __restrict__ vv_ws, float* __restrict__ gn_ws)
{
  __shared__ float sH[64], sG[64], sgv[8];
  const int v = blockIdx.x, j = threadIdx.x;
  float a = bs1[j], g = bg1[j];
  for (int k = 0; k < 768; ++k){
    const float p = Pplm[v*768 + k];
    a = fmaf(p, Ws1[k*64 + j], a);
    g = fmaf(p, Wg1[k*64 + j], g);
  }
  sH[j] = fmaxf(a, 0.f);
  sG[j] = fmaxf(g, 0.f);
  __syncthreads();
  if (j < 5){
    float acc = bs2[j];
    for (int k = 0; k < 64; ++k) acc = fmaf(sH[k], Ws2[k*5 + j], acc);
    vv_ws[v*5 + j] = acc;
  }
  if (j < 8){
    float acc = bg2[j];
    for (int k = 0; k < 64; ++k) acc = fmaf(sG[k], Wg2[k*8 + j], acc);
    sgv[j] = acc;
  }
  __syncthreads();
  if (j == 0){
    float n = 0.f;
    for (int e = 0; e < 8; ++e) n += sgv[e]*sgv[e];
    n = fmaxf(sqrtf(n), 1e-12f);
    for (int e = 0; e < 8; ++e) gn_ws[v*8 + e] = sgv[e]/n;
  }
}

// adj = softmax(gn @ gn.T, axis=-1)
__global__ __launch_bounds__(64)
void k_adj(const float* __restrict__ gn_ws, float* __restrict__ adj_ws)
{
  const int v = blockIdx.x, j = threadIdx.x;
  float sc = 0.f;
  #pragma unroll
  for (int e = 0; e < 8; ++e) sc += gn_ws[v*8+e]*gn_ws[j*8+e];
  float mx = sc;
  for (int off = 32; off > 0; off >>= 1) mx = fmaxf(mx, __shfl_xor(mx, off));
  const float ex = __expf(sc - mx);
  float sm = ex;
  for (int off = 32; off > 0; off >>= 1) sm += __shfl_xor(sm, off);
  adj_ws[v*64 + j] = ex / sm;
}

// pack gate weights: Wpack[cid][0..64]=W[q][i][o], [65]=bias, cid=(g*5+q)*32+o
__global__ __launch_bounds__(256)
void k_pack(const float* __restrict__ Wr, const float* __restrict__ br,
            const float* __restrict__ Wu, const float* __restrict__ bu,
            const float* __restrict__ Wc, const float* __restrict__ bc,
            float* __restrict__ Wpack)
{
  const int idx = blockIdx.x*256 + threadIdx.x;
  if (idx >= 480*68) return;
  const int cid = idx/68, k = idx%68;
  const int g = cid/160, qo = cid%160, q = qo/32, o = qo%32;
  const float* W  = (g==0) ? Wr : (g==1) ? Wu : Wc;
  const float* bb = (g==0) ? br : (g==1) ? bu : bc;
  float val = 0.f;
  if (k < 65)      val = W[(q*65 + k)*32 + o];
  else if (k == 65) val = bb[q*32 + o];
  Wpack[idx] = val;
}

// var_total_obs[b][v] = sum_t mask[b,t,v]
__global__ __launch_bounds__(256)
void k_vto(const float* __restrict__ P, float* __restrict__ vto_ws)
{
  const int idx = blockIdx.x*256 + threadIdx.x;
  if (idx >= BB*VV) return;
  const int b = idx/VV, v = idx%VV;
  float s = 0.f;
  for (int t = 0; t < TT; ++t) s += P[((size_t)(b*TT+t))*128 + 64 + v];
  vto_ws[idx] = s;
}

// ---------------- main recurrent kernel: 1 block per batch ----------------

__global__ __launch_bounds__(512)
void tedgn_main(const float* __restrict__ P, const float* __restrict__ Pstatic,
                const float* __restrict__ Pavg, const int* __restrict__ Plen,
                const float* __restrict__ Ptime,
                const float* __restrict__ w_val, const float* __restrict__ b_val,
                const float* __restrict__ w_per, const float* __restrict__ b_per,
                const float* __restrict__ w_lin, const float* __restrict__ b_lin,
                const float* __restrict__ emb1, const float* __restrict__ rarW,
                const float* __restrict__ Wse, const float* __restrict__ bse,
                const float* __restrict__ Wc1, const float* __restrict__ bc1,
                const float* __restrict__ Wc2, const float* __restrict__ bc2,
                const float* __restrict__ vv_ws, const float* __restrict__ adj_ws,
                const float* __restrict__ Wpack, const float* __restrict__ vto_ws,
                float* __restrict__ out)
{
  __shared__ __align__(16) float s_xh[VV][68];    // 0..31 x, 32 rarity, 33..64 h (later h_r)
  __shared__ __align__(16) float s_comb[VV][68];
  __shared__ __align__(16) float s_adj[VV][68];   // cur_adj
  __shared__ float s_adjb[VV*VV];
  __shared__ float s_rarW[VV*VV];
  __shared__ __align__(16) float s_h[VV][DD];
  __shared__ float s_u[VV][DD];
  __shared__ __align__(16) float s_out[VV][DD];
  __shared__ float s_m[VV], s_rar[VV], s_te[DD], s_feat[2*VV], s_hid[200];

  const int tid  = threadIdx.x;
  const int lane = tid & 63;
  const int w    = tid >> 6;
  const int b    = blockIdx.x;

  for (int i = tid; i < VV*DD; i += 512){ ((float*)s_h)[i] = 0.f; ((float*)s_out)[i] = 0.f; }
  for (int i = tid; i < VV*VV; i += 512){ s_adjb[i] = adj_ws[i]; s_rarW[i] = rarW[i]; }
  float vvreg[NQ];
  #pragma unroll
  for (int q = 0; q < NQ; ++q) vvreg[q] = vv_ws[lane*NQ + q];
  const float vto = vto_ws[b*VV + lane];
  const int len = Plen[b];
  __syncthreads();

  for (int t = 0; t < TT; ++t){
    // ---- P1a: mask, rarity, time embedding ----
    if (tid < VV){
      const int v = tid;
      const float m = P[((size_t)(b*TT+t))*128 + 64 + v];
      s_m[v] = m;
      const float avg = Pavg[((size_t)(b*TT+t))*VV + v];
      s_rar[v] = 0.5f * tanhfast(avg / (vto + 1.0f));
    } else if (tid < VV + DD){
      const int d = tid - VV;
      const float ttv = Ptime[b*TT + t];
      s_te[d] = (d == 0) ? fmaf(ttv, w_lin[0], b_lin[0])
                         : sinf(fmaf(ttv, w_per[d-1], b_per[d-1]));
    }
    __syncthreads();

    // ---- P1b: build x into s_xh, copy h, build cur_adj ----
    {
      const int v  = tid >> 3;
      const int d0 = (tid & 7) * 4;
      const float mv   = s_m[v];
      const float dval = P[((size_t)(b*TT+t))*128 + v];
      #pragma unroll
      for (int k = 0; k < 4; ++k){
        const int d = d0 + k;
        const float ve = fmaxf(fmaf(dval, w_val[d], b_val[d]), 0.f);
        s_xh[v][d]      = (ve + s_te[d] + emb1[v*DD + d]) * mv;
        s_xh[v][33 + d] = s_h[v][d];
      }
      if (d0 == 0) s_xh[v][32] = s_rar[v];
      const int j0 = (tid & 7) * 8;
      const float rv = s_rar[v];
      #pragma unroll
      for (int k = 0; k < 8; ++k){
        const int j = j0 + k;
        float a;
        if (j == v) a = 1.0f;
        else {
          const float onersm = fmaf(-s_rarW[v*VV + j], fabsf(rv - s_rar[j]), 1.0f);
          a = s_adjb[v*VV + j] * onersm * mv * s_m[j];
        }
        s_adj[v][j] = a;
      }
    }
    __syncthreads();

    // ---- comb = cur_adj @ [x, h] ; wave w owns columns 8w..8w+7 (+col 64 for w==7) ----
    {
      const int c0 = w * 8;
      float aAx=0,aAy=0,aAz=0,aAw=0,aBx=0,aBy=0,aBz=0,aBw=0,a64=0;
      const bool w7 = (w == 7);
      for (int j4 = 0; j4 < 16; ++j4){
        const float4 a4 = *(const float4*)&s_adj[lane][4*j4];
        #pragma unroll
        for (int jj = 0; jj < 4; ++jj){
          const int j = 4*j4 + jj;
          const float a = (jj==0)?a4.x:(jj==1)?a4.y:(jj==2)?a4.z:a4.w;
          const float4 xa = *(const float4*)&s_xh[j][c0];
          const float4 xb = *(const float4*)&s_xh[j][c0+4];
          aAx = fmaf(a, xa.x, aAx); aAy = fmaf(a, xa.y, aAy);
          aAz = fmaf(a, xa.z, aAz); aAw = fmaf(a, xa.w, aAw);
          aBx = fmaf(a, xb.x, aBx); aBy = fmaf(a, xb.y, aBy);
          aBz = fmaf(a, xb.z, aBz); aBw = fmaf(a, xb.w, aBw);
          if (w7) a64 = fmaf(a, s_xh[j][64], a64);
        }
      }
      *(float4*)&s_comb[lane][c0]   = make_float4(aAx,aAy,aAz,aAw);
      *(float4*)&s_comb[lane][c0+4] = make_float4(aBx,aBy,aBz,aBw);
      if (w7) s_comb[lane][64] = a64;
    }
    __syncthreads();

    // ---- r,u gates: waves 0-3 -> r (write h_r), waves 4-7 -> u ----
    {
      float cr[68];
      #pragma unroll
      for (int k = 0; k < 17; ++k){
        const float4 t4 = *(const float4*)&s_comb[lane][4*k];
        cr[4*k]=t4.x; cr[4*k+1]=t4.y; cr[4*k+2]=t4.z; cr[4*k+3]=t4.w;
      }
      const int g  = w >> 2;
      const int ob = (w & 3) * 8;
      #pragma clang loop unroll(disable)
      for (int cc = 0; cc < 8; ++cc){
        const int o = ob + cc;
        float acc = 0.f;
        #pragma unroll
        for (int q = 0; q < NQ; ++q){
          const float* wc = Wpack + ((size_t)((g*NQ + q)*DD + o)) * 68;
          float tmp = wc[65];
          #pragma unroll
          for (int i4 = 0; i4 < 16; ++i4){
            const float4 wv = *(const float4*)&wc[4*i4];
            tmp = fmaf(cr[4*i4  ], wv.x, tmp);
            tmp = fmaf(cr[4*i4+1], wv.y, tmp);
            tmp = fmaf(cr[4*i4+2], wv.z, tmp);
            tmp = fmaf(cr[4*i4+3], wv.w, tmp);
          }
          tmp = fmaf(cr[64], wc[64], tmp);
          acc = fmaf(vvreg[q], tmp, acc);
        }
        const float gv = sigm(acc);
        if (g == 0) s_xh[lane][33 + o] = gv * s_h[lane][o];  // h_r
        else        s_u[lane][o] = gv;
      }
    }
    __syncthreads();

    // ---- cand gate + GRU update; wave w owns o = 4w..4w+3 ----
    {
      float cr[68];
      #pragma unroll
      for (int k = 0; k < 17; ++k){
        const float4 t4 = *(const float4*)&s_xh[lane][4*k];
        cr[4*k]=t4.x; cr[4*k+1]=t4.y; cr[4*k+2]=t4.z; cr[4*k+3]=t4.w;
      }
      const int ob = w * 4;
      const bool snap = (t == len - 1);
      #pragma clang loop unroll(disable)
      for (int cc = 0; cc < 4; ++cc){
        const int o = ob + cc;
        float acc = 0.f;
        #pragma unroll
        for (int q = 0; q < NQ; ++q){
          const float* wc = Wpack + ((size_t)((10 + q)*DD + o)) * 68;
          float tmp = wc[65];
          #pragma unroll
          for (int i4 = 0; i4 < 16; ++i4){
            const float4 wv = *(const float4*)&wc[4*i4];
            tmp = fmaf(cr[4*i4  ], wv.x, tmp);
            tmp = fmaf(cr[4*i4+1], wv.y, tmp);
            tmp = fmaf(cr[4*i4+2], wv.z, tmp);
            tmp = fmaf(cr[4*i4+3], wv.w, tmp);
          }
          tmp = fmaf(cr[64], wc[64], tmp);
          acc = fmaf(vvreg[q], tmp, acc);
        }
        const float cd   = tanhfast(acc);
        const float hr   = s_xh[lane][33 + o];
        const float uu   = s_u[lane][o];
        const float hold = s_h[lane][o];
        const float hn   = fmaf(uu, cd - hr, hr);       // (1-u)*hr + u*cd
        const float hf   = (s_m[lane] > 0.5f) ? hn : hold;
        s_h[lane][o] = hf;
        if (snap) s_out[lane][o] = hf;
      }
    }
    __syncthreads();
  }

  // ---- epilogue: feat -> 200-unit MLP -> 2 logits ----
  if (tid < VV){
    float s = 0.f;
    #pragma unroll
    for (int d = 0; d < DD; ++d) s += s_out[tid][d];
    s_feat[tid] = s;
  } else if (tid < 2*VV){
    const int v = tid - VV;
    float se = bse[v];
    #pragma unroll
    for (int k = 0; k < 16; ++k) se = fmaf(Pstatic[b*16 + k], Wse[k*VV + v], se);
    s_feat[VV + v] = se;
  }
  __syncthreads();
  if (tid < 200){
    float a = bc1[tid];
    for (int k = 0; k < 128; ++k) a = fmaf(s_feat[k], Wc1[k*200 + tid], a);
    s_hid[tid] = fmaxf(a, 0.f);
  }
  __syncthreads();
  if (tid < 2){
    float a = bc2[tid];
    for (int k = 0; k < 200; ++k) a = fmaf(s_hid[k], Wc2[k*2 + tid], a);
    out[b*2 + tid] = a;
  }
}

// ---------------- launch ----------------

extern "C" void kernel_launch(void* const* d_in, const int* in_sizes, int n_in,
                              void* d_out, int out_size, void* d_ws, size_t ws_size,
                              hipStream_t stream) {
  (void)in_sizes; (void)n_in; (void)out_size; (void)ws_size;
  const float* P       = (const float*)d_in[0];
  const float* Pstatic = (const float*)d_in[1];
  const float* Pavg    = (const float*)d_in[2];
  const int*   Plen    = (const int*)  d_in[3];
  const float* Ptime   = (const float*)d_in[4];
  const float* Pplm    = (const float*)d_in[5];
  const float* w_val   = (const float*)d_in[6];
  const float* b_val   = (const float*)d_in[7];
  const float* w_per   = (const float*)d_in[8];
  const float* b_per   = (const float*)d_in[9];
  const float* w_lin   = (const float*)d_in[10];
  const float* b_lin   = (const float*)d_in[11];
  const float* emb1    = (const float*)d_in[12];
  const float* Ws1     = (const float*)d_in[13];
  const float* bs1     = (const float*)d_in[14];
  const float* Ws2     = (const float*)d_in[15];
  const float* bs2     = (const float*)d_in[16];
  const float* Wg1     = (const float*)d_in[17];
  const float* bg1     = (const float*)d_in[18];
  const float* Wg2     = (const float*)d_in[19];
  const float* bg2     = (const float*)d_in[20];
  const float* rarW    = (const float*)d_in[21];
  const float* Wu      = (const float*)d_in[22];
  const float* bu      = (const float*)d_in[23];
  const float* Wr      = (const float*)d_in[24];
  const float* br      = (const float*)d_in[25];
  const float* Wcand   = (const float*)d_in[26];
  const float* bcand   = (const float*)d_in[27];
  const float* Wse     = (const float*)d_in[28];
  const float* bse     = (const float*)d_in[29];
  const float* Wc1     = (const float*)d_in[30];
  const float* bc1     = (const float*)d_in[31];
  const float* Wc2     = (const float*)d_in[32];
  const float* bc2     = (const float*)d_in[33];

  float* ws      = (float*)d_ws;
  float* vv_ws   = ws;             // 320
  float* gn_ws   = ws + 320;       // 512
  float* adj_ws  = ws + 832;       // 4096
  float* Wpack   = ws + 4928;      // 480*68 = 32640 (16B aligned offset)
  float* vto_ws  = ws + 37568;     // 8192

  k_mlp <<<64, 64, 0, stream>>>(Pplm, Ws1, bs1, Ws2, bs2, Wg1, bg1, Wg2, bg2, vv_ws, gn_ws);
  k_adj <<<64, 64, 0, stream>>>(gn_ws, adj_ws);
  k_pack<<<(480*68 + 255)/256, 256, 0, stream>>>(Wr, br, Wu, bu, Wcand, bcand, Wpack);
  k_vto <<<(BB*VV + 255)/256, 256, 0, stream>>>(P, vto_ws);

  tedgn_main<<<BB, 512, 0, stream>>>(P, Pstatic, Pavg, Plen, Ptime,
                                     w_val, b_val, w_per, b_per, w_lin, b_lin,
                                     emb1, rarW, Wse, bse, Wc1, bc1, Wc2, bc2,
                                     vv_ws, adj_ws, Wpack, vto_ws,
                                     (float*)d_out);
}

// Round 2
// 819.182 us; speedup vs baseline: 9.6710x; 9.6710x over previous
//
#include <hip/hip_runtime.h>
#include <math.h>

#define BB 128
#define TT 128
#define VV 64
#define DD 32
#define NQ 5

typedef short bf16x8 __attribute__((ext_vector_type(8)));
typedef float f32x4 __attribute__((ext_vector_type(4)));

#define MFMA(a,b,c) __builtin_amdgcn_mfma_f32_16x16x32_bf16(a,b,c,0,0,0)

__device__ __forceinline__ float sigm(float x){ return 1.0f/(1.0f+__expf(-x)); }
__device__ __forceinline__ float tanhfast(float x){ return 2.0f/(1.0f+__expf(-2.0f*x)) - 1.0f; }
__device__ __forceinline__ unsigned short f2bf(float x){
  unsigned u = __float_as_uint(x);
  u += 0x7FFFu + ((u>>16)&1u);
  return (unsigned short)(u>>16);
}
__device__ __forceinline__ float bf2f(unsigned short h){
  return __uint_as_float(((unsigned)h)<<16);
}

// ---------------- precompute kernels ----------------

__global__ __launch_bounds__(64)
void k_mlp(const float* __restrict__ Pplm,
           const float* __restrict__ Ws1, const float* __restrict__ bs1,
           const float* __restrict__ Ws2, const float* __restrict__ bs2,
           const float* __restrict__ Wg1, const float* __restrict__ bg1,
           const float* __restrict__ Wg2, const float* __restrict__ bg2,
           float* __restrict__ vv_ws, float* __restrict__ gn_ws)
{
  __shared__ float sH[64], sG[64], sgv[8];
  const int v = blockIdx.x, j = threadIdx.x;
  float a = bs1[j], g = bg1[j];
  for (int k = 0; k < 768; ++k){
    const float p = Pplm[v*768 + k];
    a = fmaf(p, Ws1[k*64 + j], a);
    g = fmaf(p, Wg1[k*64 + j], g);
  }
  sH[j] = fmaxf(a, 0.f);
  sG[j] = fmaxf(g, 0.f);
  __syncthreads();
  if (j < 5){
    float acc = bs2[j];
    for (int k = 0; k < 64; ++k) acc = fmaf(sH[k], Ws2[k*5 + j], acc);
    vv_ws[v*5 + j] = acc;
  }
  if (j < 8){
    float acc = bg2[j];
    for (int k = 0; k < 64; ++k) acc = fmaf(sG[k], Wg2[k*8 + j], acc);
    sgv[j] = acc;
  }
  __syncthreads();
  if (j == 0){
    float n = 0.f;
    for (int e = 0; e < 8; ++e) n += sgv[e]*sgv[e];
    n = fmaxf(sqrtf(n), 1e-12f);
    for (int e = 0; e < 8; ++e) gn_ws[v*8 + e] = sgv[e]/n;
  }
}

__global__ __launch_bounds__(64)
void k_adj(const float* __restrict__ gn_ws, float* __restrict__ adj_ws)
{
  const int v = blockIdx.x, j = threadIdx.x;
  float sc = 0.f;
  #pragma unroll
  for (int e = 0; e < 8; ++e) sc += gn_ws[v*8+e]*gn_ws[j*8+e];
  float mx = sc;
  for (int off = 32; off > 0; off >>= 1) mx = fmaxf(mx, __shfl_xor(mx, off));
  const float ex = __expf(sc - mx);
  float sm = ex;
  for (int off = 32; off > 0; off >>= 1) sm += __shfl_xor(sm, off);
  adj_ws[v*64 + j] = ex / sm;
}

__global__ __launch_bounds__(256)
void k_vto(const float* __restrict__ P, float* __restrict__ vto_ws)
{
  const int idx = blockIdx.x*256 + threadIdx.x;
  if (idx >= BB*VV) return;
  const int b = idx/VV, v = idx%VV;
  float s = 0.f;
  for (int t = 0; t < TT; ++t) s += P[((size_t)(b*TT+t))*128 + 64 + v];
  vto_ws[idx] = s;
}

// pack gate weights into per-lane MFMA B-fragments (bf16) + side tables
// frag id f = ((e*2 + kt)*2 + p); element (f*64 + lane)*8 + j
// k = kt*32 + (lane>>4)*8 + j ; o = p*16 + (lane&15) ; e<5 -> r(q=e), e>=5 -> u(q=e-5)
__global__ __launch_bounds__(256)
void k_bpack(const float* __restrict__ Wr, const float* __restrict__ br,
             const float* __restrict__ Wu, const float* __restrict__ bu,
             const float* __restrict__ Wc, const float* __restrict__ bc,
             unsigned short* __restrict__ Bru, unsigned short* __restrict__ Bcn,
             float* __restrict__ sideRU, float* __restrict__ sideC)
{
  const int idx = blockIdx.x*256 + threadIdx.x;
  if (idx < 20480){
    const int f = idx >> 9, rem = idx & 511, l = rem >> 3, j = rem & 7;
    const int p = f & 1, kt = (f>>1)&1, e = f>>2;
    const int k = kt*32 + (l>>4)*8 + j;
    const int o = p*16 + (l&15);
    const int q = (e < 5) ? e : e - 5;
    const float* W = (e < 5) ? Wr : Wu;
    Bru[idx] = f2bf(W[(q*65 + k)*32 + o]);
  } else if (idx < 30720){
    const int i2 = idx - 20480;
    const int f = i2 >> 9, rem = i2 & 511, l = rem >> 3, j = rem & 7;
    const int p = f & 1, kt = (f>>1)&1, e = f>>2;
    const int k = kt*32 + (l>>4)*8 + j;
    const int o = p*16 + (l&15);
    Bcn[i2] = f2bf(Wc[(e*65 + k)*32 + o]);
  } else if (idx < 31360){
    const int i3 = idx - 30720;            // [e:10][s:2][o:32]
    const int e = i3 >> 6, s = (i3 >> 5) & 1, o = i3 & 31;
    const int q = (e < 5) ? e : e - 5;
    float v;
    if (s == 0) v = (e < 5) ? Wr[(q*65 + 64)*32 + o] : Wu[(q*65 + 64)*32 + o];
    else        v = (e < 5) ? br[q*32 + o] : bu[q*32 + o];
    sideRU[i3] = v;
  } else if (idx < 31680){
    const int i4 = idx - 31360;            // [e:5][s:2][o:32]
    const int e = i4 >> 6, s = (i4 >> 5) & 1, o = i4 & 31;
    sideC[i4] = s ? bc[e*32 + o] : Wc[(e*65 + 64)*32 + o];
  }
}

// ---------------- main recurrent kernel: 1 block (512 thr / 8 waves) per batch ----------------

__global__ __launch_bounds__(512)
void tedgn_main(const float* __restrict__ P, const float* __restrict__ Pstatic,
                const float* __restrict__ Pavg, const int* __restrict__ Plen,
                const float* __restrict__ Ptime,
                const float* __restrict__ w_val, const float* __restrict__ b_val,
                const float* __restrict__ w_per, const float* __restrict__ b_per,
                const float* __restrict__ w_lin, const float* __restrict__ b_lin,
                const float* __restrict__ emb1, const float* __restrict__ rarW,
                const float* __restrict__ Wse, const float* __restrict__ bse,
                const float* __restrict__ Wc1, const float* __restrict__ bc1,
                const float* __restrict__ Wc2, const float* __restrict__ bc2,
                const float* __restrict__ vv_ws, const float* __restrict__ adjb_ws,
                const float* __restrict__ vto_ws,
                const unsigned short* __restrict__ Bru_ws,
                const unsigned short* __restrict__ Bc_ws,
                const float* __restrict__ sideRU_ws, const float* __restrict__ sideC_ws,
                float* __restrict__ out)
{
  // LDS (≈144 KB -> 1 block/CU)
  __shared__ __align__(16) unsigned short B0Thi[80][72], B0Tlo[80][72]; // XH^T (col-major): row=XH col, k=v
  __shared__ __align__(16) unsigned short A0hi[64][72], A0lo[64][72];   // cur_adj
  __shared__ __align__(16) unsigned short A1hi[64][72], A1lo[64][72];   // comb
  __shared__ __align__(16) unsigned short A2hi[64][72], A2lo[64][72];   // [x | h_r]
  __shared__ float s_hf[64*33];
  __shared__ float s_outf[64*33];
  __shared__ float s_adjb[64*64], s_rarW[64*64];
  __shared__ float s_emb[64*32];
  __shared__ float s_vv[320];
  __shared__ float s_sideRU[640], s_sideC[320];
  __shared__ float s_m[2][64], s_rar[2][64], s_te[2][32];
  __shared__ float s_wval[32], s_bval[32];
  __shared__ float s_feat[128], s_hid[200];

  const int tid  = threadIdx.x;
  const int lane = tid & 63;
  const int w    = tid >> 6;
  const int mq   = w >> 1;        // M-quarter (16 rows)
  const int p    = w & 1;         // N parity
  const int l15  = lane & 15;
  const int l16g = lane >> 4;
  const int b    = blockIdx.x;
  const int len  = Plen[b];
  const float vto_r = (tid < VV) ? vto_ws[b*VV + tid] : 0.0f;

  // ---- prologue ----
  for (int i = tid; i < VV*VV; i += 512){ s_adjb[i] = adjb_ws[i]; s_rarW[i] = rarW[i]; }
  for (int i = tid; i < VV*DD; i += 512)  s_emb[i] = emb1[i];
  for (int i = tid; i < 64*33; i += 512){ s_hf[i] = 0.f; s_outf[i] = 0.f; }
  if (tid < 320) s_vv[tid] = vv_ws[tid];
  for (int i = tid; i < 640; i += 512) s_sideRU[i] = sideRU_ws[i];
  if (tid < 320) s_sideC[tid] = sideC_ws[tid];
  if (tid < DD){ s_wval[tid] = w_val[tid]; s_bval[tid] = b_val[tid]; }
  for (int i = tid; i < 15*72; i += 512){ B0Thi[65 + i/72][i%72] = 0; B0Tlo[65 + i/72][i%72] = 0; }

  // resident weight B-fragments
  bf16x8 Bru[10][2], Bc[5][2];
  const bf16x8* BruV = (const bf16x8*)Bru_ws;
  const bf16x8* BcV  = (const bf16x8*)Bc_ws;
  #pragma unroll
  for (int e = 0; e < 10; ++e){
    #pragma unroll
    for (int kt = 0; kt < 2; ++kt)
      Bru[e][kt] = BruV[((e*2 + kt)*2 + p)*64 + lane];
  }
  #pragma unroll
  for (int e = 0; e < 5; ++e){
    #pragma unroll
    for (int kt = 0; kt < 2; ++kt)
      Bc[e][kt] = BcV[((e*2 + kt)*2 + p)*64 + lane];
  }

  // t=0 prep
  if (tid < VV){
    const int v = tid;
    s_m[0][v] = P[((size_t)(b*TT))*128 + 64 + v];
    const float avg = Pavg[((size_t)(b*TT))*VV + v];
    s_rar[0][v] = 0.5f * tanhfast(avg / (vto_r + 1.0f));
  } else if (tid < VV + DD){
    const int d = tid - VV;
    const float ttv = Ptime[b*TT];
    s_te[0][d] = (d == 0) ? fmaf(ttv, w_lin[0], b_lin[0])
                          : __sinf(fmaf(ttv, w_per[d-1], b_per[d-1]));
  }
  __syncthreads();

  float u_r[4], hr_r[4];

  #pragma clang loop unroll(disable)
  for (int t = 0; t < TT; ++t){
    const int cur = t & 1;

    // ---- P1: build B0T (XH^T), A2 x-part, A0 (cur_adj), all hi/lo bf16 ----
    {
      const int v = tid >> 3, dg = tid & 7, d0 = dg*4;
      const float mv = s_m[cur][v];
      const float dval = P[((size_t)(b*TT + t))*128 + v];
      unsigned short xh[4], xl[4];
      #pragma unroll
      for (int k = 0; k < 4; ++k){
        const int d = d0 + k;
        const float ve = fmaxf(fmaf(dval, s_wval[d], s_bval[d]), 0.f);
        const float x = (ve + s_te[cur][d] + s_emb[v*DD + d]) * mv;
        const unsigned short h16 = f2bf(x);
        xh[k] = h16; xl[k] = f2bf(x - bf2f(h16));
        B0Thi[d][v] = h16; B0Tlo[d][v] = xl[k];
      }
      *(unsigned*)&A2hi[v][d0]     = (unsigned)xh[0] | ((unsigned)xh[1] << 16);
      *(unsigned*)&A2hi[v][d0 + 2] = (unsigned)xh[2] | ((unsigned)xh[3] << 16);
      *(unsigned*)&A2lo[v][d0]     = (unsigned)xl[0] | ((unsigned)xl[1] << 16);
      *(unsigned*)&A2lo[v][d0 + 2] = (unsigned)xl[2] | ((unsigned)xl[3] << 16);
      if (dg == 0){
        const float rv = s_rar[cur][v];
        const unsigned short rh = f2bf(rv), rl = f2bf(rv - bf2f(rh));
        A2hi[v][32] = rh; A2lo[v][32] = rl;
        B0Thi[32][v] = rh; B0Tlo[32][v] = rl;
      }
      #pragma unroll
      for (int k = 0; k < 4; ++k){
        const int d = d0 + k;
        const float hv = s_hf[v*33 + d];
        const unsigned short hh = f2bf(hv);
        B0Thi[33 + d][v] = hh; B0Tlo[33 + d][v] = f2bf(hv - bf2f(hh));
      }
      // cur_adj
      const int j0 = dg*8;
      const float rv = s_rar[cur][v];
      unsigned ah[4], al[4];
      #pragma unroll
      for (int kk = 0; kk < 8; ++kk){
        const int j = j0 + kk;
        float a;
        if (j == v) a = 1.0f;
        else {
          const float onersm = fmaf(-s_rarW[v*VV + j], fabsf(rv - s_rar[cur][j]), 1.0f);
          a = s_adjb[v*VV + j] * onersm * mv * s_m[cur][j];
        }
        const unsigned short hh = f2bf(a), ll = f2bf(a - bf2f(hh));
        if (kk & 1){ ah[kk>>1] |= ((unsigned)hh) << 16; al[kk>>1] |= ((unsigned)ll) << 16; }
        else       { ah[kk>>1] = hh; al[kk>>1] = ll; }
      }
      *(uint4*)&A0hi[v][j0] = make_uint4(ah[0], ah[1], ah[2], ah[3]);
      *(uint4*)&A0lo[v][j0] = make_uint4(al[0], al[1], al[2], al[3]);
    }
    __syncthreads();

    // ---- P2: comb = cur_adj @ XH  (MFMA, 3-product hi/lo) -> A1 hi/lo ----
    {
      const int arow = mq*16 + l15;
      const int kgo  = l16g*8;
      bf16x8 a0h[2], a0l[2];
      a0h[0] = *(const bf16x8*)&A0hi[arow][kgo];
      a0h[1] = *(const bf16x8*)&A0hi[arow][32 + kgo];
      a0l[0] = *(const bf16x8*)&A0lo[arow][kgo];
      a0l[1] = *(const bf16x8*)&A0lo[arow][32 + kgo];
      #pragma unroll
      for (int ii = 0; ii < 3; ++ii){
        const int n = 2*ii + p;
        if (n > 4) continue;
        f32x4 acc = {0.f, 0.f, 0.f, 0.f};
        #pragma unroll
        for (int kt = 0; kt < 2; ++kt){
          const bf16x8 bh = *(const bf16x8*)&B0Thi[n*16 + l15][kt*32 + kgo];
          const bf16x8 bl = *(const bf16x8*)&B0Tlo[n*16 + l15][kt*32 + kgo];
          acc = MFMA(a0h[kt], bh, acc);
          acc = MFMA(a0l[kt], bh, acc);
          acc = MFMA(a0h[kt], bl, acc);
        }
        const int col = n*16 + l15;
        if (col <= 64){
          #pragma unroll
          for (int j = 0; j < 4; ++j){
            const int row = mq*16 + l16g*4 + j;
            const float dv = acc[j];
            const unsigned short hh = f2bf(dv);
            A1hi[row][col] = hh;
            A1lo[row][col] = f2bf(dv - bf2f(hh));
          }
        }
      }
    }
    __syncthreads();

    // ---- P3: r,u gates (MFMA A1 x Bru) + in-register combine ----
    {
      const int arow = mq*16 + l15;
      const int kgo  = l16g*8;
      const int o    = p*16 + l15;
      bf16x8 aH[2], aL[2];
      aH[0] = *(const bf16x8*)&A1hi[arow][kgo];
      aH[1] = *(const bf16x8*)&A1hi[arow][32 + kgo];
      aL[0] = *(const bf16x8*)&A1lo[arow][kgo];
      aL[1] = *(const bf16x8*)&A1lo[arow][32 + kgo];
      float a64f[4];
      #pragma unroll
      for (int j = 0; j < 4; ++j){
        const int vj = mq*16 + l16g*4 + j;
        a64f[j] = bf2f(A1hi[vj][64]) + bf2f(A1lo[vj][64]);
      }
      f32x4 acc[10];
      #pragma unroll
      for (int e = 0; e < 10; ++e){
        const float w64 = s_sideRU[e*64 + o];
        const float bs  = s_sideRU[e*64 + 32 + o];
        #pragma unroll
        for (int j = 0; j < 4; ++j) acc[e][j] = fmaf(a64f[j], w64, bs);
      }
      #pragma unroll
      for (int kt = 0; kt < 2; ++kt){
        #pragma unroll
        for (int e = 0; e < 10; ++e){
          acc[e] = MFMA(aH[kt], Bru[e][kt], acc[e]);
          acc[e] = MFMA(aL[kt], Bru[e][kt], acc[e]);
        }
      }
      #pragma unroll
      for (int j = 0; j < 4; ++j){
        const int vj = mq*16 + l16g*4 + j;
        const float* vvp = &s_vv[vj*NQ];
        const float pr = vvp[0]*acc[0][j] + vvp[1]*acc[1][j] + vvp[2]*acc[2][j]
                       + vvp[3]*acc[3][j] + vvp[4]*acc[4][j];
        const float pu = vvp[0]*acc[5][j] + vvp[1]*acc[6][j] + vvp[2]*acc[7][j]
                       + vvp[3]*acc[8][j] + vvp[4]*acc[9][j];
        const float r = sigm(pr);
        u_r[j] = sigm(pu);
        const float hrv = r * s_hf[vj*33 + o];
        hr_r[j] = hrv;
        const unsigned short hh = f2bf(hrv);
        A2hi[vj][33 + o] = hh;
        A2lo[vj][33 + o] = f2bf(hrv - bf2f(hh));
      }
    }
    __syncthreads();

    // ---- P4: cand gate (MFMA A2 x Bc) + GRU update + next-step prep ----
    {
      const int arow = mq*16 + l15;
      const int kgo  = l16g*8;
      const int o    = p*16 + l15;
      bf16x8 aH[2], aL[2];
      aH[0] = *(const bf16x8*)&A2hi[arow][kgo];
      aH[1] = *(const bf16x8*)&A2hi[arow][32 + kgo];
      aL[0] = *(const bf16x8*)&A2lo[arow][kgo];
      aL[1] = *(const bf16x8*)&A2lo[arow][32 + kgo];
      float a64f[4];
      #pragma unroll
      for (int j = 0; j < 4; ++j){
        const int vj = mq*16 + l16g*4 + j;
        a64f[j] = bf2f(A2hi[vj][64]) + bf2f(A2lo[vj][64]);
      }
      f32x4 acc[5];
      #pragma unroll
      for (int e = 0; e < 5; ++e){
        const float w64 = s_sideC[e*64 + o];
        const float bs  = s_sideC[e*64 + 32 + o];
        #pragma unroll
        for (int j = 0; j < 4; ++j) acc[e][j] = fmaf(a64f[j], w64, bs);
      }
      #pragma unroll
      for (int kt = 0; kt < 2; ++kt){
        #pragma unroll
        for (int e = 0; e < 5; ++e){
          acc[e] = MFMA(aH[kt], Bc[e][kt], acc[e]);
          acc[e] = MFMA(aL[kt], Bc[e][kt], acc[e]);
        }
      }
      #pragma unroll
      for (int j = 0; j < 4; ++j){
        const int vj = mq*16 + l16g*4 + j;
        const float* vvp = &s_vv[vj*NQ];
        const float pc = vvp[0]*acc[0][j] + vvp[1]*acc[1][j] + vvp[2]*acc[2][j]
                       + vvp[3]*acc[3][j] + vvp[4]*acc[4][j];
        const float cd = tanhfast(pc);
        const float hold = s_hf[vj*33 + o];
        const float hn = fmaf(u_r[j], cd - hr_r[j], hr_r[j]);
        const float hf = (s_m[cur][vj] > 0.5f) ? hn : hold;
        s_hf[vj*33 + o] = hf;
        if (t == len - 1) s_outf[vj*33 + o] = hf;
      }
      // next-step prep (double-buffered)
      if (t < TT - 1){
        const int nxt = cur ^ 1;
        if (tid < VV){
          const int v = tid;
          s_m[nxt][v] = P[((size_t)(b*TT + t + 1))*128 + 64 + v];
          const float avg = Pavg[((size_t)(b*TT + t + 1))*VV + v];
          s_rar[nxt][v] = 0.5f * tanhfast(avg / (vto_r + 1.0f));
        } else if (tid < VV + DD){
          const int d = tid - VV;
          const float ttv = Ptime[b*TT + t + 1];
          s_te[nxt][d] = (d == 0) ? fmaf(ttv, w_lin[0], b_lin[0])
                                  : __sinf(fmaf(ttv, w_per[d-1], b_per[d-1]));
        }
      }
    }
    __syncthreads();
  }

  // ---- epilogue: feat -> 200-unit MLP -> 2 logits ----
  if (tid < VV){
    float s = 0.f;
    #pragma unroll
    for (int d = 0; d < DD; ++d) s += s_outf[tid*33 + d];
    s_feat[tid] = s;
  } else if (tid < 2*VV){
    const int v = tid - VV;
    float se = bse[v];
    #pragma unroll
    for (int k = 0; k < 16; ++k) se = fmaf(Pstatic[b*16 + k], Wse[k*VV + v], se);
    s_feat[VV + v] = se;
  }
  __syncthreads();
  if (tid < 200){
    float a = bc1[tid];
    for (int k = 0; k < 128; ++k) a = fmaf(s_feat[k], Wc1[k*200 + tid], a);
    s_hid[tid] = fmaxf(a, 0.f);
  }
  __syncthreads();
  if (tid < 2){
    float a = bc2[tid];
    for (int k = 0; k < 200; ++k) a = fmaf(s_hid[k], Wc2[k*2 + tid], a);
    out[b*2 + tid] = a;
  }
}

// ---------------- launch ----------------

extern "C" void kernel_launch(void* const* d_in, const int* in_sizes, int n_in,
                              void* d_out, int out_size, void* d_ws, size_t ws_size,
                              hipStream_t stream) {
  (void)in_sizes; (void)n_in; (void)out_size; (void)ws_size;
  const float* P       = (const float*)d_in[0];
  const float* Pstatic = (const float*)d_in[1];
  const float* Pavg    = (const float*)d_in[2];
  const int*   Plen    = (const int*)  d_in[3];
  const float* Ptime   = (const float*)d_in[4];
  const float* Pplm    = (const float*)d_in[5];
  const float* w_val   = (const float*)d_in[6];
  const float* b_val   = (const float*)d_in[7];
  const float* w_per   = (const float*)d_in[8];
  const float* b_per   = (const float*)d_in[9];
  const float* w_lin   = (const float*)d_in[10];
  const float* b_lin   = (const float*)d_in[11];
  const float* emb1    = (const float*)d_in[12];
  const float* Ws1     = (const float*)d_in[13];
  const float* bs1     = (const float*)d_in[14];
  const float* Ws2     = (const float*)d_in[15];
  const float* bs2     = (const float*)d_in[16];
  const float* Wg1     = (const float*)d_in[17];
  const float* bg1     = (const float*)d_in[18];
  const float* Wg2     = (const float*)d_in[19];
  const float* bg2     = (const float*)d_in[20];
  const float* rarW    = (const float*)d_in[21];
  const float* Wu      = (const float*)d_in[22];
  const float* bu      = (const float*)d_in[23];
  const float* Wr      = (const float*)d_in[24];
  const float* br      = (const float*)d_in[25];
  const float* Wcand   = (const float*)d_in[26];
  const float* bcand   = (const float*)d_in[27];
  const float* Wse     = (const float*)d_in[28];
  const float* bse     = (const float*)d_in[29];
  const float* Wc1     = (const float*)d_in[30];
  const float* bc1     = (const float*)d_in[31];
  const float* Wc2     = (const float*)d_in[32];
  const float* bc2     = (const float*)d_in[33];

  float* ws = (float*)d_ws;
  float*          vv_ws   = ws;                 // 320 f
  float*          gn_ws   = ws + 320;           // 512 f
  float*          adjb_ws = ws + 832;           // 4096 f
  float*          vto_ws  = ws + 4928;          // 8192 f
  unsigned short* Bru_ws  = (unsigned short*)(ws + 13120);   // 20480 u16 (16B aligned)
  unsigned short* Bc_ws   = (unsigned short*)(ws + 23360);   // 10240 u16 (16B aligned)
  float*          sideRU_ws = ws + 28480;       // 640 f
  float*          sideC_ws  = ws + 29120;       // 320 f

  k_mlp  <<<64, 64, 0, stream>>>(Pplm, Ws1, bs1, Ws2, bs2, Wg1, bg1, Wg2, bg2, vv_ws, gn_ws);
  k_adj  <<<64, 64, 0, stream>>>(gn_ws, adjb_ws);
  k_vto  <<<(BB*VV + 255)/256, 256, 0, stream>>>(P, vto_ws);
  k_bpack<<<124, 256, 0, stream>>>(Wr, br, Wu, bu, Wcand, bcand, Bru_ws, Bc_ws, sideRU_ws, sideC_ws);

  tedgn_main<<<BB, 512, 0, stream>>>(P, Pstatic, Pavg, Plen, Ptime,
                                     w_val, b_val, w_per, b_per, w_lin, b_lin,
                                     emb1, rarW, Wse, bse, Wc1, bc1, Wc2, bc2,
                                     vv_ws, adjb_ws, vto_ws,
                                     Bru_ws, Bc_ws, sideRU_ws, sideC_ws,
                                     (float*)d_out);
}

// Round 3
// 797.796 us; speedup vs baseline: 9.9303x; 1.0268x over previous
//
#include <hip/hip_runtime.h>
#include <math.h>

#define BB 128
#define TT 128
#define VV 64
#define DD 32
#define NQ 5

typedef short bf16x8 __attribute__((ext_vector_type(8)));
typedef float f32x4 __attribute__((ext_vector_type(4)));

#define MFMA(a,b,c) __builtin_amdgcn_mfma_f32_16x16x32_bf16(a,b,c,0,0,0)

__device__ __forceinline__ float sigm(float x){ return 1.0f/(1.0f+__expf(-x)); }
__device__ __forceinline__ float tanhfast(float x){ return 2.0f/(1.0f+__expf(-2.0f*x)) - 1.0f; }
__device__ __forceinline__ unsigned short f2bf(float x){
  unsigned u = __float_as_uint(x);
  u += 0x7FFFu + ((u>>16)&1u);
  return (unsigned short)(u>>16);
}
__device__ __forceinline__ float bf2f(unsigned short h){
  return __uint_as_float(((unsigned)h)<<16);
}

// ---------------- precompute kernels ----------------

__global__ __launch_bounds__(64)
void k_mlp(const float* __restrict__ Pplm,
           const float* __restrict__ Ws1, const float* __restrict__ bs1,
           const float* __restrict__ Ws2, const float* __restrict__ bs2,
           const float* __restrict__ Wg1, const float* __restrict__ bg1,
           const float* __restrict__ Wg2, const float* __restrict__ bg2,
           float* __restrict__ vv_ws, float* __restrict__ gn_ws)
{
  __shared__ float sH[64], sG[64], sgv[8];
  const int v = blockIdx.x, j = threadIdx.x;
  float a = bs1[j], g = bg1[j];
  for (int k = 0; k < 768; ++k){
    const float p = Pplm[v*768 + k];
    a = fmaf(p, Ws1[k*64 + j], a);
    g = fmaf(p, Wg1[k*64 + j], g);
  }
  sH[j] = fmaxf(a, 0.f);
  sG[j] = fmaxf(g, 0.f);
  __syncthreads();
  if (j < 5){
    float acc = bs2[j];
    for (int k = 0; k < 64; ++k) acc = fmaf(sH[k], Ws2[k*5 + j], acc);
    vv_ws[v*5 + j] = acc;
  }
  if (j < 8){
    float acc = bg2[j];
    for (int k = 0; k < 64; ++k) acc = fmaf(sG[k], Wg2[k*8 + j], acc);
    sgv[j] = acc;
  }
  __syncthreads();
  if (j == 0){
    float n = 0.f;
    for (int e = 0; e < 8; ++e) n += sgv[e]*sgv[e];
    n = fmaxf(sqrtf(n), 1e-12f);
    for (int e = 0; e < 8; ++e) gn_ws[v*8 + e] = sgv[e]/n;
  }
}

__global__ __launch_bounds__(64)
void k_adj(const float* __restrict__ gn_ws, float* __restrict__ adj_ws)
{
  const int v = blockIdx.x, j = threadIdx.x;
  float sc = 0.f;
  #pragma unroll
  for (int e = 0; e < 8; ++e) sc += gn_ws[v*8+e]*gn_ws[j*8+e];
  float mx = sc;
  for (int off = 32; off > 0; off >>= 1) mx = fmaxf(mx, __shfl_xor(mx, off));
  const float ex = __expf(sc - mx);
  float sm = ex;
  for (int off = 32; off > 0; off >>= 1) sm += __shfl_xor(sm, off);
  adj_ws[v*64 + j] = ex / sm;
}

__global__ __launch_bounds__(256)
void k_vto(const float* __restrict__ P, float* __restrict__ vto_ws)
{
  const int idx = blockIdx.x*256 + threadIdx.x;
  if (idx >= BB*VV) return;
  const int b = idx/VV, v = idx%VV;
  float s = 0.f;
  for (int t = 0; t < TT; ++t) s += P[((size_t)(b*TT+t))*128 + 64 + v];
  vto_ws[idx] = s;
}

// pack gate weights into per-lane MFMA B-fragments (bf16) + side tables
// frag id f = ((e*2 + kt)*2 + p); element (f*64 + lane)*8 + j
// r/u: k = kt*32 + (lane>>4)*8 + j ; o = p*16 + (lane&15)
// cand: K-order permuted to [x(0..31) | h_r(0..31) | rarity(side)]:
//   k' = kt*32 + (lane>>4)*8 + j ; orig_k = (k'<32) ? k' : k'+1 ; side = orig k=32
__global__ __launch_bounds__(256)
void k_bpack(const float* __restrict__ Wr, const float* __restrict__ br,
             const float* __restrict__ Wu, const float* __restrict__ bu,
             const float* __restrict__ Wc, const float* __restrict__ bc,
             unsigned short* __restrict__ Bru, unsigned short* __restrict__ Bcn,
             float* __restrict__ sideRU, float* __restrict__ sideC)
{
  const int idx = blockIdx.x*256 + threadIdx.x;
  if (idx < 20480){
    const int f = idx >> 9, rem = idx & 511, l = rem >> 3, j = rem & 7;
    const int p = f & 1, kt = (f>>1)&1, e = f>>2;
    const int k = kt*32 + (l>>4)*8 + j;
    const int o = p*16 + (l&15);
    const int q = (e < 5) ? e : e - 5;
    const float* W = (e < 5) ? Wr : Wu;
    Bru[idx] = f2bf(W[(q*65 + k)*32 + o]);
  } else if (idx < 30720){
    const int i2 = idx - 20480;
    const int f = i2 >> 9, rem = i2 & 511, l = rem >> 3, j = rem & 7;
    const int p = f & 1, kt = (f>>1)&1, e = f>>2;
    const int kp = kt*32 + (l>>4)*8 + j;
    const int k = (kp < 32) ? kp : kp + 1;
    const int o = p*16 + (l&15);
    Bcn[i2] = f2bf(Wc[(e*65 + k)*32 + o]);
  } else if (idx < 31360){
    const int i3 = idx - 30720;            // [e:10][s:2][o:32]
    const int e = i3 >> 6, s = (i3 >> 5) & 1, o = i3 & 31;
    const int q = (e < 5) ? e : e - 5;
    float v;
    if (s == 0) v = (e < 5) ? Wr[(q*65 + 64)*32 + o] : Wu[(q*65 + 64)*32 + o];
    else        v = (e < 5) ? br[q*32 + o] : bu[q*32 + o];
    sideRU[i3] = v;
  } else if (idx < 31680){
    const int i4 = idx - 31360;            // [e:5][s:2][o:32]
    const int e = i4 >> 6, s = (i4 >> 5) & 1, o = i4 & 31;
    sideC[i4] = s ? bc[e*32 + o] : Wc[(e*65 + 32)*32 + o];   // side = rarity weight
  }
}

// ---------------- main recurrent kernel: 1 block (512 thr / 8 waves) per batch ----------------

__global__ __launch_bounds__(512, 1)
void tedgn_main(const float* __restrict__ P, const float* __restrict__ Pstatic,
                const float* __restrict__ Pavg, const int* __restrict__ Plen,
                const float* __restrict__ Ptime,
                const float* __restrict__ w_val, const float* __restrict__ b_val,
                const float* __restrict__ w_per, const float* __restrict__ b_per,
                const float* __restrict__ w_lin, const float* __restrict__ b_lin,
                const float* __restrict__ emb1, const float* __restrict__ rarW,
                const float* __restrict__ Wse, const float* __restrict__ bse,
                const float* __restrict__ Wc1, const float* __restrict__ bc1,
                const float* __restrict__ Wc2, const float* __restrict__ bc2,
                const float* __restrict__ vv_ws, const float* __restrict__ adjb_ws,
                const float* __restrict__ vto_ws,
                const unsigned short* __restrict__ Bru_ws,
                const unsigned short* __restrict__ Bc_ws,
                const float* __restrict__ sideRU_ws, const float* __restrict__ sideC_ws,
                float* __restrict__ out)
{
  __shared__ __align__(16) unsigned short B0Thi[80][72], B0Tlo[80][72]; // XH^T: row=feature (0..31 x, 32 rar, 33..64 h), col=v
  __shared__ __align__(16) unsigned short A0hi[64][72], A0lo[64][72];   // cur_adj
  __shared__ __align__(16) unsigned short A1hi[64][72], A1lo[64][72];   // comb
  __shared__ __align__(16) unsigned short A2xhi[2][64][40], A2xlo[2][64][40]; // x rows (dbuf)
  __shared__ __align__(16) unsigned short A2hhi[64][40], A2hlo[64][40];       // h_r rows
  __shared__ float s_adjb[64*64], s_rarW[64*64];
  __shared__ float s_outf[64][33];
  __shared__ float s_m[2][64], s_rar[2][64], s_te[2][32], s_dval[2][64];
  __shared__ float s_vv[320], s_sideRU[640], s_sideC[320];
  __shared__ float s_feat[128], s_hid[200];

  const int tid  = threadIdx.x;
  const int lane = tid & 63;
  const int w    = tid >> 6;
  const int mq   = w >> 1;
  const int p    = w & 1;
  const int l15  = lane & 15;
  const int l16g = lane >> 4;
  const int kgo  = l16g * 8;
  const int b    = blockIdx.x;
  const int len  = Plen[b];

  // v-major identity (A2x, A0 builds)
  const int vm_v = tid >> 3, vm_dg = tid & 7, vm_d0 = vm_dg*4, vm_j0 = vm_dg*8;
  // d-major identity (B0T-x build), valid tid<256
  const int dm_d = tid >> 3, dm_vg = tid & 7, dm_v0 = dm_vg*8;
  // per-thread output rows
  const int vj0 = mq*16 + l16g*4;
  const int oo  = p*16 + l15;

  // persistent regs
  float vm_wv[4], vm_bv[4], vm_emb[4];
  #pragma unroll
  for (int k = 0; k < 4; ++k){
    vm_wv[k] = w_val[vm_d0 + k];
    vm_bv[k] = b_val[vm_d0 + k];
    vm_emb[k] = emb1[vm_v*DD + vm_d0 + k];
  }
  float dm_wv = 0.f, dm_bv = 0.f, dm_emb[8];
  if (tid < 256){
    dm_wv = w_val[dm_d]; dm_bv = b_val[dm_d];
    #pragma unroll
    for (int i = 0; i < 8; ++i) dm_emb[i] = emb1[(dm_v0 + i)*DD + dm_d];
  }
  const int te_d = tid - 128;
  float te_w = 0.f, te_b = 0.f;
  if (tid >= 128 && tid < 160){
    te_w = (te_d == 0) ? w_lin[0] : w_per[te_d - 1];
    te_b = (te_d == 0) ? b_lin[0] : b_per[te_d - 1];
  }
  const float vto_r = (tid < 64) ? vto_ws[b*VV + tid] : 0.f;

  // LDS constant fills
  for (int i = tid; i < VV*VV; i += 512){ s_adjb[i] = adjb_ws[i]; s_rarW[i] = rarW[i]; }
  if (tid < 320) s_vv[tid] = vv_ws[tid];
  for (int i = tid; i < 640; i += 512) s_sideRU[i] = sideRU_ws[i];
  if (tid < 320) s_sideC[tid] = sideC_ws[tid];
  for (int i = tid; i < 47*72; i += 512){ const int r = 33 + i/72, c = i%72; B0Thi[r][c] = 0; B0Tlo[r][c] = 0; }

  // resident weight B-fragments
  bf16x8 Bru[10][2], Bc[5][2];
  {
    const bf16x8* BruV = (const bf16x8*)Bru_ws;
    const bf16x8* BcV  = (const bf16x8*)Bc_ws;
    #pragma unroll
    for (int e = 0; e < 10; ++e)
      #pragma unroll
      for (int kt = 0; kt < 2; ++kt)
        Bru[e][kt] = BruV[((e*2 + kt)*2 + p)*64 + lane];
    #pragma unroll
    for (int e = 0; e < 5; ++e)
      #pragma unroll
      for (int kt = 0; kt < 2; ++kt)
        Bc[e][kt] = BcV[((e*2 + kt)*2 + p)*64 + lane];
  }

  // prologue prep(t=0)
  if (tid < 64){
    s_dval[0][tid] = P[((size_t)(b*TT))*128 + tid];
    s_m[0][tid]    = P[((size_t)(b*TT))*128 + 64 + tid];
    const float av = Pavg[((size_t)(b*TT))*VV + tid];
    s_rar[0][tid]  = 0.5f * tanhfast(av / (vto_r + 1.f));
  } else if (tid >= 128 && tid < 160){
    const float ptv = Ptime[b*TT];
    s_te[0][te_d] = (te_d == 0) ? fmaf(ptv, te_w, te_b) : __sinf(fmaf(ptv, te_w, te_b));
  }
  __syncthreads();

  // builds x/adj structures for step referenced by buffer ni
  auto build = [&](int ni){
    // v-major: A2x rows (x features 0..31)
    {
      const float dv = s_dval[ni][vm_v];
      const float mv = s_m[ni][vm_v];
      unsigned xh2[2], xl2[2];
      #pragma unroll
      for (int k = 0; k < 4; ++k){
        const float ve = fmaxf(fmaf(dv, vm_wv[k], vm_bv[k]), 0.f);
        const float x  = (ve + s_te[ni][vm_d0 + k] + vm_emb[k]) * mv;
        const unsigned short hh = f2bf(x);
        const unsigned short ll = f2bf(x - bf2f(hh));
        if (k & 1){ xh2[k>>1] |= ((unsigned)hh) << 16; xl2[k>>1] |= ((unsigned)ll) << 16; }
        else      { xh2[k>>1] = hh; xl2[k>>1] = ll; }
      }
      *(uint2*)&A2xhi[ni][vm_v][vm_d0] = make_uint2(xh2[0], xh2[1]);
      *(uint2*)&A2xlo[ni][vm_v][vm_d0] = make_uint2(xl2[0], xl2[1]);
    }
    // d-major: B0T x rows 0..31 (vectorized row writes)
    if (tid < 256){
      const float te = s_te[ni][dm_d];
      unsigned hh4[4], ll4[4];
      #pragma unroll
      for (int i = 0; i < 8; ++i){
        const float dv = s_dval[ni][dm_v0 + i];
        const float mv = s_m[ni][dm_v0 + i];
        const float ve = fmaxf(fmaf(dv, dm_wv, dm_bv), 0.f);
        const float x  = (ve + te + dm_emb[i]) * mv;
        const unsigned short hh = f2bf(x);
        const unsigned short ll = f2bf(x - bf2f(hh));
        if (i & 1){ hh4[i>>1] |= ((unsigned)hh) << 16; ll4[i>>1] |= ((unsigned)ll) << 16; }
        else      { hh4[i>>1] = hh; ll4[i>>1] = ll; }
      }
      *(uint4*)&B0Thi[dm_d][dm_v0] = make_uint4(hh4[0], hh4[1], hh4[2], hh4[3]);
      *(uint4*)&B0Tlo[dm_d][dm_v0] = make_uint4(ll4[0], ll4[1], ll4[2], ll4[3]);
    } else if (tid < 264){
      const int v0 = (tid & 7) * 8;
      unsigned hh4[4], ll4[4];
      #pragma unroll
      for (int i = 0; i < 8; ++i){
        const float rv = s_rar[ni][v0 + i];
        const unsigned short hh = f2bf(rv);
        const unsigned short ll = f2bf(rv - bf2f(hh));
        if (i & 1){ hh4[i>>1] |= ((unsigned)hh) << 16; ll4[i>>1] |= ((unsigned)ll) << 16; }
        else      { hh4[i>>1] = hh; ll4[i>>1] = ll; }
      }
      *(uint4*)&B0Thi[32][v0] = make_uint4(hh4[0], hh4[1], hh4[2], hh4[3]);
      *(uint4*)&B0Tlo[32][v0] = make_uint4(ll4[0], ll4[1], ll4[2], ll4[3]);
    }
    // A0 (cur_adj), v-major: 8 cols per thread
    {
      const float mv = s_m[ni][vm_v];
      const float rv = s_rar[ni][vm_v];
      unsigned ah[4], al[4];
      #pragma unroll
      for (int kk = 0; kk < 8; ++kk){
        const int j = vm_j0 + kk;
        float a;
        if (j == vm_v) a = 1.0f;
        else {
          const float onersm = fmaf(-s_rarW[vm_v*VV + j], fabsf(rv - s_rar[ni][j]), 1.0f);
          a = s_adjb[vm_v*VV + j] * onersm * mv * s_m[ni][j];
        }
        const unsigned short hh = f2bf(a), ll = f2bf(a - bf2f(hh));
        if (kk & 1){ ah[kk>>1] |= ((unsigned)hh) << 16; al[kk>>1] |= ((unsigned)ll) << 16; }
        else       { ah[kk>>1] = hh; al[kk>>1] = ll; }
      }
      *(uint4*)&A0hi[vm_v][vm_j0] = make_uint4(ah[0], ah[1], ah[2], ah[3]);
      *(uint4*)&A0lo[vm_v][vm_j0] = make_uint4(al[0], al[1], al[2], al[3]);
    }
  };

  build(0);
  float h_reg[4] = {0.f,0.f,0.f,0.f};
  float out_reg[4] = {0.f,0.f,0.f,0.f};
  float u_r[4], hr_r[4];
  __syncthreads();

  #pragma clang loop unroll(disable)
  for (int t = 0; t < TT; ++t){
    const int cur = t & 1, nxt = cur ^ 1;

    // ---- P2: issue next-step global loads, then comb = cur_adj @ XH ----
    float pld = 0.f, pavg = 0.f, ptv = 0.f;
    if (t + 1 < TT){
      if (tid < 128) pld = P[((size_t)(b*TT + t + 1))*128 + tid];
      if (tid < 64)  pavg = Pavg[((size_t)(b*TT + t + 1))*VV + tid];
      if (tid >= 128 && tid < 160) ptv = Ptime[b*TT + t + 1];
    }
    {
      const int arow = mq*16 + l15;
      bf16x8 a0h[2], a0l[2];
      a0h[0] = *(const bf16x8*)&A0hi[arow][kgo];
      a0h[1] = *(const bf16x8*)&A0hi[arow][32 + kgo];
      a0l[0] = *(const bf16x8*)&A0lo[arow][kgo];
      a0l[1] = *(const bf16x8*)&A0lo[arow][32 + kgo];
      __builtin_amdgcn_s_setprio(1);
      #pragma unroll
      for (int ii = 0; ii < 3; ++ii){
        const int n = 2*ii + p;
        if (n > 4) continue;
        f32x4 acc = {0.f, 0.f, 0.f, 0.f};
        #pragma unroll
        for (int kt = 0; kt < 2; ++kt){
          const bf16x8 bh = *(const bf16x8*)&B0Thi[n*16 + l15][kt*32 + kgo];
          const bf16x8 bl = *(const bf16x8*)&B0Tlo[n*16 + l15][kt*32 + kgo];
          acc = MFMA(a0h[kt], bh, acc);
          acc = MFMA(a0l[kt], bh, acc);
          acc = MFMA(a0h[kt], bl, acc);
        }
        __builtin_amdgcn_s_setprio(0);
        const int col = n*16 + l15;
        if (col <= 64){
          #pragma unroll
          for (int j = 0; j < 4; ++j){
            const float dv = acc[j];
            const unsigned short hh = f2bf(dv);
            A1hi[vj0 + j][col] = hh;
            A1lo[vj0 + j][col] = f2bf(dv - bf2f(hh));
          }
        }
        __builtin_amdgcn_s_setprio(1);
      }
      __builtin_amdgcn_s_setprio(0);
    }
    __syncthreads();   // barrier1

    // ---- P3: next-step prep writes + r,u gates + h_r ----
    if (t + 1 < TT){
      if (tid < 64){
        s_dval[nxt][tid] = pld;
        s_rar[nxt][tid]  = 0.5f * tanhfast(pavg / (vto_r + 1.f));
      } else if (tid < 128){
        s_m[nxt][tid - 64] = pld;
      } else if (tid < 160){
        s_te[nxt][te_d] = (te_d == 0) ? fmaf(ptv, te_w, te_b) : __sinf(fmaf(ptv, te_w, te_b));
      }
    }
    {
      const int arow = mq*16 + l15;
      bf16x8 aH[2], aL[2];
      aH[0] = *(const bf16x8*)&A1hi[arow][kgo];
      aH[1] = *(const bf16x8*)&A1hi[arow][32 + kgo];
      aL[0] = *(const bf16x8*)&A1lo[arow][kgo];
      aL[1] = *(const bf16x8*)&A1lo[arow][32 + kgo];
      float a64f[4];
      #pragma unroll
      for (int j = 0; j < 4; ++j)
        a64f[j] = bf2f(A1hi[vj0 + j][64]) + bf2f(A1lo[vj0 + j][64]);
      f32x4 acc[10];
      #pragma unroll
      for (int e = 0; e < 10; ++e){
        const float w64 = s_sideRU[e*64 + oo];
        const float bs  = s_sideRU[e*64 + 32 + oo];
        #pragma unroll
        for (int j = 0; j < 4; ++j) acc[e][j] = fmaf(a64f[j], w64, bs);
      }
      __builtin_amdgcn_s_setprio(1);
      #pragma unroll
      for (int kt = 0; kt < 2; ++kt)
        #pragma unroll
        for (int e = 0; e < 10; ++e){
          acc[e] = MFMA(aH[kt], Bru[e][kt], acc[e]);
          acc[e] = MFMA(aL[kt], Bru[e][kt], acc[e]);
        }
      __builtin_amdgcn_s_setprio(0);
      #pragma unroll
      for (int j = 0; j < 4; ++j){
        const int vj = vj0 + j;
        const float* vvp = &s_vv[vj*NQ];
        const float pr = vvp[0]*acc[0][j] + vvp[1]*acc[1][j] + vvp[2]*acc[2][j]
                       + vvp[3]*acc[3][j] + vvp[4]*acc[4][j];
        const float pu = vvp[0]*acc[5][j] + vvp[1]*acc[6][j] + vvp[2]*acc[7][j]
                       + vvp[3]*acc[8][j] + vvp[4]*acc[9][j];
        const float r = sigm(pr);
        u_r[j] = sigm(pu);
        const float hrv = r * h_reg[j];
        hr_r[j] = hrv;
        const unsigned short hh = f2bf(hrv);
        A2hhi[vj][oo] = hh;
        A2hlo[vj][oo] = f2bf(hrv - bf2f(hh));
      }
    }
    __syncthreads();   // barrier2

    // ---- P4: cand + GRU update + h->B0T + build(t+1) ----
    {
      const int arow = mq*16 + l15;
      const bf16x8 aH0 = *(const bf16x8*)&A2xhi[cur][arow][kgo];
      const bf16x8 aL0 = *(const bf16x8*)&A2xlo[cur][arow][kgo];
      const bf16x8 aH1 = *(const bf16x8*)&A2hhi[arow][kgo];
      const bf16x8 aL1 = *(const bf16x8*)&A2hlo[arow][kgo];
      float rar_j[4];
      #pragma unroll
      for (int j = 0; j < 4; ++j) rar_j[j] = s_rar[cur][vj0 + j];
      f32x4 acc[5];
      #pragma unroll
      for (int e = 0; e < 5; ++e){
        const float w64 = s_sideC[e*64 + oo];
        const float bs  = s_sideC[e*64 + 32 + oo];
        #pragma unroll
        for (int j = 0; j < 4; ++j) acc[e][j] = fmaf(rar_j[j], w64, bs);
      }
      __builtin_amdgcn_s_setprio(1);
      #pragma unroll
      for (int e = 0; e < 5; ++e){
        acc[e] = MFMA(aH0, Bc[e][0], acc[e]);
        acc[e] = MFMA(aL0, Bc[e][0], acc[e]);
        acc[e] = MFMA(aH1, Bc[e][1], acc[e]);
        acc[e] = MFMA(aL1, Bc[e][1], acc[e]);
      }
      __builtin_amdgcn_s_setprio(0);
      #pragma unroll
      for (int j = 0; j < 4; ++j){
        const int vj = vj0 + j;
        const float* vvp = &s_vv[vj*NQ];
        const float pc = vvp[0]*acc[0][j] + vvp[1]*acc[1][j] + vvp[2]*acc[2][j]
                       + vvp[3]*acc[3][j] + vvp[4]*acc[4][j];
        const float cd = tanhfast(pc);
        const float hn = fmaf(u_r[j], cd - hr_r[j], hr_r[j]);
        const float hf = (s_m[cur][vj] > 0.5f) ? hn : h_reg[j];
        h_reg[j] = hf;
        if (t == len - 1) out_reg[j] = hf;
        const unsigned short hh = f2bf(hf);
        B0Thi[33 + oo][vj] = hh;
        B0Tlo[33 + oo][vj] = f2bf(hf - bf2f(hh));
      }
      if (t + 1 < TT) build(nxt);
    }
    __syncthreads();   // barrier0 (loop top for t+1)
  }

  // ---- epilogue ----
  #pragma unroll
  for (int j = 0; j < 4; ++j) s_outf[vj0 + j][oo] = out_reg[j];
  __syncthreads();
  if (tid < VV){
    float s = 0.f;
    #pragma unroll
    for (int d = 0; d < DD; ++d) s += s_outf[tid][d];
    s_feat[tid] = s;
  } else if (tid < 2*VV){
    const int v = tid - VV;
    float se = bse[v];
    #pragma unroll
    for (int k = 0; k < 16; ++k) se = fmaf(Pstatic[b*16 + k], Wse[k*VV + v], se);
    s_feat[VV + v] = se;
  }
  __syncthreads();
  if (tid < 200){
    float a = bc1[tid];
    for (int k = 0; k < 128; ++k) a = fmaf(s_feat[k], Wc1[k*200 + tid], a);
    s_hid[tid] = fmaxf(a, 0.f);
  }
  __syncthreads();
  if (tid < 2){
    float a = bc2[tid];
    for (int k = 0; k < 200; ++k) a = fmaf(s_hid[k], Wc2[k*2 + tid], a);
    out[b*2 + tid] = a;
  }
}

// ---------------- launch ----------------

extern "C" void kernel_launch(void* const* d_in, const int* in_sizes, int n_in,
                              void* d_out, int out_size, void* d_ws, size_t ws_size,
                              hipStream_t stream) {
  (void)in_sizes; (void)n_in; (void)out_size; (void)ws_size;
  const float* P       = (const float*)d_in[0];
  const float* Pstatic = (const float*)d_in[1];
  const float* Pavg    = (const float*)d_in[2];
  const int*   Plen    = (const int*)  d_in[3];
  const float* Ptime   = (const float*)d_in[4];
  const float* Pplm    = (const float*)d_in[5];
  const float* w_val   = (const float*)d_in[6];
  const float* b_val   = (const float*)d_in[7];
  const float* w_per   = (const float*)d_in[8];
  const float* b_per   = (const float*)d_in[9];
  const float* w_lin   = (const float*)d_in[10];
  const float* b_lin   = (const float*)d_in[11];
  const float* emb1    = (const float*)d_in[12];
  const float* Ws1     = (const float*)d_in[13];
  const float* bs1     = (const float*)d_in[14];
  const float* Ws2     = (const float*)d_in[15];
  const float* bs2     = (const float*)d_in[16];
  const float* Wg1     = (const float*)d_in[17];
  const float* bg1     = (const float*)d_in[18];
  const float* Wg2     = (const float*)d_in[19];
  const float* bg2     = (const float*)d_in[20];
  const float* rarW    = (const float*)d_in[21];
  const float* Wu      = (const float*)d_in[22];
  const float* bu      = (const float*)d_in[23];
  const float* Wr      = (const float*)d_in[24];
  const float* br      = (const float*)d_in[25];
  const float* Wcand   = (const float*)d_in[26];
  const float* bcand   = (const float*)d_in[27];
  const float* Wse     = (const float*)d_in[28];
  const float* bse     = (const float*)d_in[29];
  const float* Wc1     = (const float*)d_in[30];
  const float* bc1     = (const float*)d_in[31];
  const float* Wc2     = (const float*)d_in[32];
  const float* bc2     = (const float*)d_in[33];

  float* ws = (float*)d_ws;
  float*          vv_ws   = ws;                 // 320 f
  float*          gn_ws   = ws + 320;           // 512 f
  float*          adjb_ws = ws + 832;           // 4096 f
  float*          vto_ws  = ws + 4928;          // 8192 f
  unsigned short* Bru_ws  = (unsigned short*)(ws + 13120);   // 20480 u16
  unsigned short* Bc_ws   = (unsigned short*)(ws + 23360);   // 10240 u16
  float*          sideRU_ws = ws + 28480;       // 640 f
  float*          sideC_ws  = ws + 29120;       // 320 f

  k_mlp  <<<64, 64, 0, stream>>>(Pplm, Ws1, bs1, Ws2, bs2, Wg1, bg1, Wg2, bg2, vv_ws, gn_ws);
  k_adj  <<<64, 64, 0, stream>>>(gn_ws, adjb_ws);
  k_vto  <<<(BB*VV + 255)/256, 256, 0, stream>>>(P, vto_ws);
  k_bpack<<<124, 256, 0, stream>>>(Wr, br, Wu, bu, Wcand, bcand, Bru_ws, Bc_ws, sideRU_ws, sideC_ws);

  tedgn_main<<<BB, 512, 0, stream>>>(P, Pstatic, Pavg, Plen, Ptime,
                                     w_val, b_val, w_per, b_per, w_lin, b_lin,
                                     emb1, rarW, Wse, bse, Wc1, bc1, Wc2, bc2,
                                     vv_ws, adjb_ws, vto_ws,
                                     Bru_ws, Bc_ws, sideRU_ws, sideC_ws,
                                     (float*)d_out);
}

// Round 5
// 776.333 us; speedup vs baseline: 10.2048x; 1.0276x over previous
//
#include <hip/hip_runtime.h>
#include <math.h>

#define BB 128
#define TT 128
#define VV 64
#define DD 32
#define NQ 5

typedef short bf16x8 __attribute__((ext_vector_type(8)));
typedef float f32x4 __attribute__((ext_vector_type(4)));

#define MFMA(a,b,c) __builtin_amdgcn_mfma_f32_16x16x32_bf16(a,b,c,0,0,0)

__device__ __forceinline__ float sigm(float x){ return 1.0f/(1.0f+__expf(-x)); }
__device__ __forceinline__ float tanhfast(float x){ return 2.0f/(1.0f+__expf(-2.0f*x)) - 1.0f; }
__device__ __forceinline__ unsigned short f2bf(float x){
  unsigned u = __float_as_uint(x);
  u += 0x7FFFu + ((u>>16)&1u);
  return (unsigned short)(u>>16);
}
__device__ __forceinline__ float bf2f(unsigned short h){
  return __uint_as_float(((unsigned)h)<<16);
}

union bfu { bf16x8 v; unsigned u[4]; unsigned short s[8]; };

// split 8 floats -> hi bf16x8 + lo bf16x8 (lo = rne(x - f32(hi))) — pure C, RNE
__device__ __forceinline__ void split8(const float* x, bfu& H, bfu& L){
  #pragma unroll
  for (int i = 0; i < 8; ++i){
    const unsigned short hh = f2bf(x[i]);
    H.s[i] = hh;
    L.s[i] = f2bf(x[i] - bf2f(hh));
  }
}

// ---------------- precompute kernels ----------------

__global__ __launch_bounds__(64)
void k_mlp(const float* __restrict__ Pplm,
           const float* __restrict__ Ws1, const float* __restrict__ bs1,
           const float* __restrict__ Ws2, const float* __restrict__ bs2,
           const float* __restrict__ Wg1, const float* __restrict__ bg1,
           const float* __restrict__ Wg2, const float* __restrict__ bg2,
           float* __restrict__ vv_ws, float* __restrict__ gn_ws)
{
  __shared__ float sH[64], sG[64], sgv[8];
  const int v = blockIdx.x, j = threadIdx.x;
  float a = bs1[j], g = bg1[j];
  for (int k = 0; k < 768; ++k){
    const float p = Pplm[v*768 + k];
    a = fmaf(p, Ws1[k*64 + j], a);
    g = fmaf(p, Wg1[k*64 + j], g);
  }
  sH[j] = fmaxf(a, 0.f);
  sG[j] = fmaxf(g, 0.f);
  __syncthreads();
  if (j < 5){
    float acc = bs2[j];
    for (int k = 0; k < 64; ++k) acc = fmaf(sH[k], Ws2[k*5 + j], acc);
    vv_ws[v*5 + j] = acc;
  }
  if (j < 8){
    float acc = bg2[j];
    for (int k = 0; k < 64; ++k) acc = fmaf(sG[k], Wg2[k*8 + j], acc);
    sgv[j] = acc;
  }
  __syncthreads();
  if (j == 0){
    float n = 0.f;
    for (int e = 0; e < 8; ++e) n += sgv[e]*sgv[e];
    n = fmaxf(sqrtf(n), 1e-12f);
    for (int e = 0; e < 8; ++e) gn_ws[v*8 + e] = sgv[e]/n;
  }
}

__global__ __launch_bounds__(64)
void k_adj(const float* __restrict__ gn_ws, float* __restrict__ adj_ws)
{
  const int v = blockIdx.x, j = threadIdx.x;
  float sc = 0.f;
  #pragma unroll
  for (int e = 0; e < 8; ++e) sc += gn_ws[v*8+e]*gn_ws[j*8+e];
  float mx = sc;
  for (int off = 32; off > 0; off >>= 1) mx = fmaxf(mx, __shfl_xor(mx, off));
  const float ex = __expf(sc - mx);
  float sm = ex;
  for (int off = 32; off > 0; off >>= 1) sm += __shfl_xor(sm, off);
  adj_ws[v*64 + j] = ex / sm;
}

__global__ __launch_bounds__(256)
void k_vto(const float* __restrict__ P, float* __restrict__ vto_ws)
{
  const int idx = blockIdx.x*256 + threadIdx.x;
  if (idx >= BB*VV) return;
  const int b = idx/VV, v = idx%VV;
  float s = 0.f;
  for (int t = 0; t < TT; ++t) s += P[((size_t)(b*TT+t))*128 + 64 + v];
  vto_ws[idx] = s;
}

// pack gate weights into per-lane MFMA B-fragments (bf16) + side tables
__global__ __launch_bounds__(256)
void k_bpack(const float* __restrict__ Wr, const float* __restrict__ br,
             const float* __restrict__ Wu, const float* __restrict__ bu,
             const float* __restrict__ Wc, const float* __restrict__ bc,
             unsigned short* __restrict__ Bru, unsigned short* __restrict__ Bcn,
             float* __restrict__ sideRU, float* __restrict__ sideC)
{
  const int idx = blockIdx.x*256 + threadIdx.x;
  if (idx < 20480){
    const int f = idx >> 9, rem = idx & 511, l = rem >> 3, j = rem & 7;
    const int p = f & 1, kt = (f>>1)&1, e = f>>2;
    const int k = kt*32 + (l>>4)*8 + j;
    const int o = p*16 + (l&15);
    const int q = (e < 5) ? e : e - 5;
    const float* W = (e < 5) ? Wr : Wu;
    Bru[idx] = f2bf(W[(q*65 + k)*32 + o]);
  } else if (idx < 30720){
    const int i2 = idx - 20480;
    const int f = i2 >> 9, rem = i2 & 511, l = rem >> 3, j = rem & 7;
    const int p = f & 1, kt = (f>>1)&1, e = f>>2;
    const int kp = kt*32 + (l>>4)*8 + j;
    const int k = (kp < 32) ? kp : kp + 1;
    const int o = p*16 + (l&15);
    Bcn[i2] = f2bf(Wc[(e*65 + k)*32 + o]);
  } else if (idx < 31360){
    const int i3 = idx - 30720;            // [e:10][s:2][o:32]
    const int e = i3 >> 6, s = (i3 >> 5) & 1, o = i3 & 31;
    const int q = (e < 5) ? e : e - 5;
    float v;
    if (s == 0) v = (e < 5) ? Wr[(q*65 + 64)*32 + o] : Wu[(q*65 + 64)*32 + o];
    else        v = (e < 5) ? br[q*32 + o] : bu[q*32 + o];
    sideRU[i3] = v;
  } else if (idx < 31680){
    const int i4 = idx - 31360;            // [e:5][s:2][o:32]
    const int e = i4 >> 6, s = (i4 >> 5) & 1, o = i4 & 31;
    sideC[i4] = s ? bc[e*32 + o] : Wc[(e*65 + 32)*32 + o];   // s=0: rarity weight
  }
}

// ---------------- main recurrent kernel: 1 block (256 thr / 4 waves) per batch ----------------

__global__ __launch_bounds__(256, 1)
void tedgn_main(const float* __restrict__ P, const float* __restrict__ Pstatic,
                const float* __restrict__ Pavg, const int* __restrict__ Plen,
                const float* __restrict__ Ptime,
                const float* __restrict__ w_val, const float* __restrict__ b_val,
                const float* __restrict__ w_per, const float* __restrict__ b_per,
                const float* __restrict__ w_lin, const float* __restrict__ b_lin,
                const float* __restrict__ emb1, const float* __restrict__ rarW,
                const float* __restrict__ Wse, const float* __restrict__ bse,
                const float* __restrict__ Wc1, const float* __restrict__ bc1,
                const float* __restrict__ Wc2, const float* __restrict__ bc2,
                const float* __restrict__ vv_ws, const float* __restrict__ adjb_ws,
                const float* __restrict__ vto_ws,
                const unsigned short* __restrict__ Bru_ws,
                const unsigned short* __restrict__ Bc_ws,
                const float* __restrict__ sideRU_ws, const float* __restrict__ sideC_ws,
                float* __restrict__ out)
{
  // XH^T double-buffered: [buf][hi/lo][feature 0..79][v 0..79 pad]
  __shared__ __align__(16) unsigned short B0T[2][2][80][80];
  __shared__ __align__(16) float A1f[4][16][68];   // per-wave comb rows (f32)
  __shared__ __align__(16) float hrF[4][16][36];   // per-wave h_r rows (f32)
  __shared__ __align__(16) float s_rar[2][64];
  __shared__ __align__(16) float s_m[2][64];
  __shared__ float s_sru[640], s_scd[320];
  __shared__ float s_outf[64][33];
  __shared__ float s_feat[128], s_hid[200];

  const int tid  = threadIdx.x;
  const int lane = tid & 63;
  const int wid  = tid >> 6;      // 4 waves; wave owns rows R..R+15
  const int l15  = lane & 15;
  const int l16g = lane >> 4;
  const int kgo  = l16g * 8;
  const int R    = wid * 16;
  const int v_own = R + l15;
  const int b    = blockIdx.x;
  const int len  = Plen[b];

  // LDS side tables
  for (int i = tid; i < 640; i += 256) s_sru[i] = sideRU_ws[i];
  for (int i = tid; i < 320; i += 256) s_scd[i] = sideC_ws[i];
  // zero the padding feature rows 65..79 of BOTH buffers (read as B for the n=4 tile)
  for (int i = tid; i < 2*2*15*80; i += 256){
    const int c  = i % 80;
    const int r  = 65 + (i / 80) % 15;
    const int hl = (i / 1200) % 2;
    const int bb = i / 2400;
    B0T[bb][hl][r][c] = 0;
  }

  // resident weight B-fragments (VGPRs)
  bf16x8 Wru[10][2][2], Wcd[5][2][2];
  {
    const bf16x8* BruV = (const bf16x8*)Bru_ws;
    const bf16x8* BcV  = (const bf16x8*)Bc_ws;
    #pragma unroll
    for (int e = 0; e < 10; ++e)
      #pragma unroll
      for (int kt = 0; kt < 2; ++kt)
        #pragma unroll
        for (int p2 = 0; p2 < 2; ++p2)
          Wru[e][kt][p2] = BruV[((e*2 + kt)*2 + p2)*64 + lane];
    #pragma unroll
    for (int e = 0; e < 5; ++e)
      #pragma unroll
      for (int kt = 0; kt < 2; ++kt)
        #pragma unroll
        for (int p2 = 0; p2 < 2; ++p2)
          Wcd[e][kt][p2] = BcV[((e*2 + kt)*2 + p2)*64 + lane];
  }

  // per-lane constants
  float adjb_r[2][8], rarW_r[2][8];
  #pragma unroll
  for (int kt = 0; kt < 2; ++kt)
    #pragma unroll
    for (int j = 0; j < 8; ++j){
      adjb_r[kt][j] = adjb_ws[v_own*64 + kt*32 + kgo + j];
      rarW_r[kt][j] = rarW   [v_own*64 + kt*32 + kgo + j];
    }
  float embr[8], wvr[8], bvr[8], wpr[8], bpr[8];
  #pragma unroll
  for (int j = 0; j < 8; ++j){
    const int d = kgo + j;
    embr[j] = emb1[v_own*DD + d];
    wvr[j]  = w_val[d];
    bvr[j]  = b_val[d];
    wpr[j]  = (d == 0) ? w_lin[0] : w_per[d-1];
    bpr[j]  = (d == 0) ? b_lin[0] : b_per[d-1];
  }
  float vvr[4][NQ];
  #pragma unroll
  for (int j = 0; j < 4; ++j)
    #pragma unroll
    for (int q = 0; q < NQ; ++q)
      vvr[j][q] = vv_ws[(R + l16g*4 + j)*NQ + q];
  const float vto_own = vto_ws[b*VV + v_own];

  float h[2][4]    = {{0.f,0.f,0.f,0.f},{0.f,0.f,0.f,0.f}};
  float outr[2][4] = {{0.f,0.f,0.f,0.f},{0.f,0.f,0.f,0.f}};
  bfu xfH, xfL;
  float rar_own, m_own;

  // ---- prologue: build step-0 state into buf 0 ----
  {
    const float pd = P[(size_t)(b*TT)*128 + v_own];
    const float pm = P[(size_t)(b*TT)*128 + 64 + v_own];
    const float pa = Pavg[(size_t)(b*TT)*VV + v_own];
    const float pt = Ptime[b*TT];
    const float rar_n = 0.5f * tanhfast(pa / (vto_own + 1.f));
    float xv[8];
    #pragma unroll
    for (int j = 0; j < 8; ++j){
      const int d = kgo + j;
      const float tearg = fmaf(pt, wpr[j], bpr[j]);
      const float te = (d == 0) ? tearg : __sinf(tearg);
      const float ve = fmaxf(fmaf(pd, wvr[j], bvr[j]), 0.f);
      xv[j] = (ve + te + embr[j]) * pm;
    }
    split8(xv, xfH, xfL);
    #pragma unroll
    for (int j = 0; j < 8; ++j){
      B0T[0][0][kgo + j][v_own] = xfH.s[j];
      B0T[0][1][kgo + j][v_own] = xfL.s[j];
    }
    *(uint2*)&B0T[0][0][33 + l15][R + l16g*4] = make_uint2(0u, 0u);
    *(uint2*)&B0T[0][1][33 + l15][R + l16g*4] = make_uint2(0u, 0u);
    *(uint2*)&B0T[0][0][49 + l15][R + l16g*4] = make_uint2(0u, 0u);
    *(uint2*)&B0T[0][1][49 + l15][R + l16g*4] = make_uint2(0u, 0u);
    if (l16g == 0){
      s_rar[0][v_own] = rar_n;
      s_m[0][v_own]   = pm;
      const unsigned short rh = f2bf(rar_n);
      B0T[0][0][32][v_own] = rh;
      B0T[0][1][32][v_own] = f2bf(rar_n - bf2f(rh));
    }
    rar_own = rar_n;
    m_own   = pm;
  }
  __syncthreads();

  #pragma clang loop unroll(disable)
  for (int t = 0; t < TT; ++t){
    const int cur = t & 1, nxt = cur ^ 1;

    // prefetch t+1 (consumed in tail)
    float pd = 0.f, pm = 0.f, pa = 0.f, pt = 0.f;
    const bool more = (t + 1 < TT);
    if (more){
      pd = P[(size_t)(b*TT + t + 1)*128 + v_own];
      pm = P[(size_t)(b*TT + t + 1)*128 + 64 + v_own];
      pa = Pavg[(size_t)(b*TT + t + 1)*VV + v_own];
      pt = Ptime[b*TT + t + 1];
    }

    // ---- adj A-fragments (in-register) ----
    bfu aAh[2], aAl[2];
    #pragma unroll
    for (int kt = 0; kt < 2; ++kt){
      const float4 r0 = *(const float4*)&s_rar[cur][kt*32 + kgo];
      const float4 r1 = *(const float4*)&s_rar[cur][kt*32 + kgo + 4];
      const float4 m0 = *(const float4*)&s_m[cur][kt*32 + kgo];
      const float4 m1 = *(const float4*)&s_m[cur][kt*32 + kgo + 4];
      const float rj[8] = {r0.x,r0.y,r0.z,r0.w,r1.x,r1.y,r1.z,r1.w};
      const float mj[8] = {m0.x,m0.y,m0.z,m0.w,m1.x,m1.y,m1.z,m1.w};
      float av[8];
      #pragma unroll
      for (int j = 0; j < 8; ++j){
        const int k = kt*32 + kgo + j;
        const float e1 = fmaf(-rarW_r[kt][j], fabsf(rar_own - rj[j]), 1.0f);
        const float a  = adjb_r[kt][j] * e1 * (m_own * mj[j]);
        av[j] = (k == v_own) ? 1.0f : a;
      }
      split8(av, aAh[kt], aAl[kt]);
    }

    // ---- comb = cur_adj @ XH (3-product hi/lo) -> A1f (f32, wave-private) ----
    #pragma unroll
    for (int n = 0; n < 5; ++n){
      f32x4 acc = {0.f,0.f,0.f,0.f};
      #pragma unroll
      for (int kt = 0; kt < 2; ++kt){
        const bf16x8 bh = *(const bf16x8*)&B0T[cur][0][n*16 + l15][kt*32 + kgo];
        const bf16x8 bl = *(const bf16x8*)&B0T[cur][1][n*16 + l15][kt*32 + kgo];
        acc = MFMA(aAh[kt].v, bh, acc);
        acc = MFMA(aAl[kt].v, bh, acc);
        acc = MFMA(aAh[kt].v, bl, acc);
      }
      const int col = n*16 + l15;
      if (col < 68){
        #pragma unroll
        for (int j = 0; j < 4; ++j) A1f[wid][l16g*4 + j][col] = acc[j];
      }
    }
    __builtin_amdgcn_sched_barrier(0);   // keep A1f stores before the reads below

    // ---- gate A-fragments from comb (same-wave LDS round trip) ----
    bfu aH[2], aL[2];
    #pragma unroll
    for (int kt = 0; kt < 2; ++kt){
      float xv[8];
      *(float4*)&xv[0] = *(const float4*)&A1f[wid][l15][kt*32 + kgo];
      *(float4*)&xv[4] = *(const float4*)&A1f[wid][l15][kt*32 + kgo + 4];
      split8(xv, aH[kt], aL[kt]);
    }
    float a64f[4];
    #pragma unroll
    for (int j = 0; j < 4; ++j) a64f[j] = A1f[wid][l16g*4 + j][64];

    // ---- r gates ----
    float hr[2][4];
    {
      f32x4 ag[5][2];
      #pragma unroll
      for (int e = 0; e < 5; ++e)
        #pragma unroll
        for (int p2 = 0; p2 < 2; ++p2){
          const int o = p2*16 + l15;
          const float w64 = s_sru[e*64 + o];
          const float bs  = s_sru[e*64 + 32 + o];
          #pragma unroll
          for (int j = 0; j < 4; ++j) ag[e][p2][j] = fmaf(a64f[j], w64, bs);
        }
      #pragma unroll
      for (int e = 0; e < 5; ++e)
        #pragma unroll
        for (int p2 = 0; p2 < 2; ++p2){
          ag[e][p2] = MFMA(aH[0].v, Wru[e][0][p2], ag[e][p2]);
          ag[e][p2] = MFMA(aL[0].v, Wru[e][0][p2], ag[e][p2]);
          ag[e][p2] = MFMA(aH[1].v, Wru[e][1][p2], ag[e][p2]);
          ag[e][p2] = MFMA(aL[1].v, Wru[e][1][p2], ag[e][p2]);
        }
      #pragma unroll
      for (int p2 = 0; p2 < 2; ++p2)
        #pragma unroll
        for (int j = 0; j < 4; ++j){
          const float pr = vvr[j][0]*ag[0][p2][j] + vvr[j][1]*ag[1][p2][j]
                         + vvr[j][2]*ag[2][p2][j] + vvr[j][3]*ag[3][p2][j]
                         + vvr[j][4]*ag[4][p2][j];
          hr[p2][j] = sigm(pr) * h[p2][j];
          hrF[wid][l16g*4 + j][p2*16 + l15] = hr[p2][j];
        }
    }
    __builtin_amdgcn_sched_barrier(0);   // keep hrF stores before cand reads

    // ---- u gates ----
    float uu[2][4];
    {
      f32x4 ag[5][2];
      #pragma unroll
      for (int e = 0; e < 5; ++e)
        #pragma unroll
        for (int p2 = 0; p2 < 2; ++p2){
          const int o = p2*16 + l15;
          const float w64 = s_sru[(5 + e)*64 + o];
          const float bs  = s_sru[(5 + e)*64 + 32 + o];
          #pragma unroll
          for (int j = 0; j < 4; ++j) ag[e][p2][j] = fmaf(a64f[j], w64, bs);
        }
      #pragma unroll
      for (int e = 0; e < 5; ++e)
        #pragma unroll
        for (int p2 = 0; p2 < 2; ++p2){
          ag[e][p2] = MFMA(aH[0].v, Wru[5+e][0][p2], ag[e][p2]);
          ag[e][p2] = MFMA(aL[0].v, Wru[5+e][0][p2], ag[e][p2]);
          ag[e][p2] = MFMA(aH[1].v, Wru[5+e][1][p2], ag[e][p2]);
          ag[e][p2] = MFMA(aL[1].v, Wru[5+e][1][p2], ag[e][p2]);
        }
      #pragma unroll
      for (int p2 = 0; p2 < 2; ++p2)
        #pragma unroll
        for (int j = 0; j < 4; ++j){
          const float pu = vvr[j][0]*ag[0][p2][j] + vvr[j][1]*ag[1][p2][j]
                         + vvr[j][2]*ag[2][p2][j] + vvr[j][3]*ag[3][p2][j]
                         + vvr[j][4]*ag[4][p2][j];
          uu[p2][j] = sigm(pu);
        }
    }

    // ---- cand + GRU update ----
    {
      bfu hH, hL;
      {
        float hv[8];
        *(float4*)&hv[0] = *(const float4*)&hrF[wid][l15][kgo];
        *(float4*)&hv[4] = *(const float4*)&hrF[wid][l15][kgo + 4];
        split8(hv, hH, hL);
      }
      float rar_cj[4], m_cj[4];
      #pragma unroll
      for (int j = 0; j < 4; ++j){
        rar_cj[j] = s_rar[cur][R + l16g*4 + j];
        m_cj[j]   = s_m[cur][R + l16g*4 + j];
      }
      f32x4 ag[5][2];
      #pragma unroll
      for (int e = 0; e < 5; ++e)
        #pragma unroll
        for (int p2 = 0; p2 < 2; ++p2){
          const int o = p2*16 + l15;
          const float w32 = s_scd[e*64 + o];
          const float bs  = s_scd[e*64 + 32 + o];
          #pragma unroll
          for (int j = 0; j < 4; ++j) ag[e][p2][j] = fmaf(rar_cj[j], w32, bs);
        }
      #pragma unroll
      for (int e = 0; e < 5; ++e)
        #pragma unroll
        for (int p2 = 0; p2 < 2; ++p2){
          ag[e][p2] = MFMA(xfH.v, Wcd[e][0][p2], ag[e][p2]);
          ag[e][p2] = MFMA(xfL.v, Wcd[e][0][p2], ag[e][p2]);
          ag[e][p2] = MFMA(hH.v,  Wcd[e][1][p2], ag[e][p2]);
          ag[e][p2] = MFMA(hL.v,  Wcd[e][1][p2], ag[e][p2]);
        }
      const bool snap = (t == len - 1);
      #pragma unroll
      for (int p2 = 0; p2 < 2; ++p2)
        #pragma unroll
        for (int j = 0; j < 4; ++j){
          const float pc = vvr[j][0]*ag[0][p2][j] + vvr[j][1]*ag[1][p2][j]
                         + vvr[j][2]*ag[2][p2][j] + vvr[j][3]*ag[3][p2][j]
                         + vvr[j][4]*ag[4][p2][j];
          const float cd = tanhfast(pc);
          const float hn = fmaf(uu[p2][j], cd - hr[p2][j], hr[p2][j]);
          const float hf = (m_cj[j] > 0.5f) ? hn : h[p2][j];
          h[p2][j] = hf;
          if (snap) outr[p2][j] = hf;
        }
    }

    // ---- write h to B0T[nxt] ----
    {
      float h8[8] = {h[0][0],h[0][1],h[0][2],h[0][3],h[1][0],h[1][1],h[1][2],h[1][3]};
      bfu HH, HL;
      split8(h8, HH, HL);
      *(uint2*)&B0T[nxt][0][33 + l15][R + l16g*4] = make_uint2(HH.u[0], HH.u[1]);
      *(uint2*)&B0T[nxt][1][33 + l15][R + l16g*4] = make_uint2(HL.u[0], HL.u[1]);
      *(uint2*)&B0T[nxt][0][49 + l15][R + l16g*4] = make_uint2(HH.u[2], HH.u[3]);
      *(uint2*)&B0T[nxt][1][49 + l15][R + l16g*4] = make_uint2(HL.u[2], HL.u[3]);
    }

    // ---- next-step x / rar / tables into buf nxt ----
    if (more){
      const float rar_n = 0.5f * tanhfast(pa / (vto_own + 1.f));
      float xv[8];
      #pragma unroll
      for (int j = 0; j < 8; ++j){
        const int d = kgo + j;
        const float tearg = fmaf(pt, wpr[j], bpr[j]);
        const float te = (d == 0) ? tearg : __sinf(tearg);
        const float ve = fmaxf(fmaf(pd, wvr[j], bvr[j]), 0.f);
        xv[j] = (ve + te + embr[j]) * pm;
      }
      split8(xv, xfH, xfL);
      #pragma unroll
      for (int j = 0; j < 8; ++j){
        B0T[nxt][0][kgo + j][v_own] = xfH.s[j];
        B0T[nxt][1][kgo + j][v_own] = xfL.s[j];
      }
      if (l16g == 0){
        s_rar[nxt][v_own] = rar_n;
        s_m[nxt][v_own]   = pm;
        const unsigned short rh = f2bf(rar_n);
        B0T[nxt][0][32][v_own] = rh;
        B0T[nxt][1][32][v_own] = f2bf(rar_n - bf2f(rh));
      }
      rar_own = rar_n;
      m_own   = pm;
    }
    __syncthreads();
  }

  // ---- epilogue: feat -> 200-unit MLP -> 2 logits ----
  #pragma unroll
  for (int p2 = 0; p2 < 2; ++p2)
    #pragma unroll
    for (int j = 0; j < 4; ++j)
      s_outf[R + l16g*4 + j][p2*16 + l15] = outr[p2][j];
  __syncthreads();
  if (tid < VV){
    float s = 0.f;
    #pragma unroll
    for (int d = 0; d < DD; ++d) s += s_outf[tid][d];
    s_feat[tid] = s;
  } else if (tid < 2*VV){
    const int v = tid - VV;
    float se = bse[v];
    #pragma unroll
    for (int k = 0; k < 16; ++k) se = fmaf(Pstatic[b*16 + k], Wse[k*VV + v], se);
    s_feat[VV + v] = se;
  }
  __syncthreads();
  if (tid < 200){
    float a = bc1[tid];
    for (int k = 0; k < 128; ++k) a = fmaf(s_feat[k], Wc1[k*200 + tid], a);
    s_hid[tid] = fmaxf(a, 0.f);
  }
  __syncthreads();
  if (tid < 2){
    float a = bc2[tid];
    for (int k = 0; k < 200; ++k) a = fmaf(s_hid[k], Wc2[k*2 + tid], a);
    out[b*2 + tid] = a;
  }
}

// ---------------- launch ----------------

extern "C" void kernel_launch(void* const* d_in, const int* in_sizes, int n_in,
                              void* d_out, int out_size, void* d_ws, size_t ws_size,
                              hipStream_t stream) {
  (void)in_sizes; (void)n_in; (void)out_size; (void)ws_size;
  const float* P       = (const float*)d_in[0];
  const float* Pstatic = (const float*)d_in[1];
  const float* Pavg    = (const float*)d_in[2];
  const int*   Plen    = (const int*)  d_in[3];
  const float* Ptime   = (const float*)d_in[4];
  const float* Pplm    = (const float*)d_in[5];
  const float* w_val   = (const float*)d_in[6];
  const float* b_val   = (const float*)d_in[7];
  const float* w_per   = (const float*)d_in[8];
  const float* b_per   = (const float*)d_in[9];
  const float* w_lin   = (const float*)d_in[10];
  const float* b_lin   = (const float*)d_in[11];
  const float* emb1    = (const float*)d_in[12];
  const float* Ws1     = (const float*)d_in[13];
  const float* bs1     = (const float*)d_in[14];
  const float* Ws2     = (const float*)d_in[15];
  const float* bs2     = (const float*)d_in[16];
  const float* Wg1     = (const float*)d_in[17];
  const float* bg1     = (const float*)d_in[18];
  const float* Wg2     = (const float*)d_in[19];
  const float* bg2     = (const float*)d_in[20];
  const float* rarW    = (const float*)d_in[21];
  const float* Wu      = (const float*)d_in[22];
  const float* bu      = (const float*)d_in[23];
  const float* Wr      = (const float*)d_in[24];
  const float* br      = (const float*)d_in[25];
  const float* Wcand   = (const float*)d_in[26];
  const float* bcand   = (const float*)d_in[27];
  const float* Wse     = (const float*)d_in[28];
  const float* bse     = (const float*)d_in[29];
  const float* Wc1     = (const float*)d_in[30];
  const float* bc1     = (const float*)d_in[31];
  const float* Wc2     = (const float*)d_in[32];
  const float* bc2     = (const float*)d_in[33];

  float* ws = (float*)d_ws;
  float*          vv_ws   = ws;                 // 320 f
  float*          gn_ws   = ws + 320;           // 512 f
  float*          adjb_ws = ws + 832;           // 4096 f
  float*          vto_ws  = ws + 4928;          // 8192 f
  unsigned short* Bru_ws  = (unsigned short*)(ws + 13120);   // 20480 u16
  unsigned short* Bc_ws   = (unsigned short*)(ws + 23360);   // 10240 u16
  float*          sideRU_ws = ws + 28480;       // 640 f
  float*          sideC_ws  = ws + 29120;       // 320 f

  k_mlp  <<<64, 64, 0, stream>>>(Pplm, Ws1, bs1, Ws2, bs2, Wg1, bg1, Wg2, bg2, vv_ws, gn_ws);
  k_adj  <<<64, 64, 0, stream>>>(gn_ws, adjb_ws);
  k_vto  <<<(BB*VV + 255)/256, 256, 0, stream>>>(P, vto_ws);
  k_bpack<<<124, 256, 0, stream>>>(Wr, br, Wu, bu, Wcand, bcand, Bru_ws, Bc_ws, sideRU_ws, sideC_ws);

  tedgn_main<<<BB, 256, 0, stream>>>(P, Pstatic, Pavg, Plen, Ptime,
                                     w_val, b_val, w_per, b_per, w_lin, b_lin,
                                     emb1, rarW, Wse, bse, Wc1, bc1, Wc2, bc2,
                                     vv_ws, adjb_ws, vto_ws,
                                     Bru_ws, Bc_ws, sideRU_ws, sideC_ws,
                                     (float*)d_out);
}

// Round 6
// 660.729 us; speedup vs baseline: 11.9903x; 1.1750x over previous
//
#include <hip/hip_runtime.h>
#include <math.h>

#define BB 128
#define TT 128
#define VV 64
#define DD 32
#define NQ 5

typedef short bf16x8 __attribute__((ext_vector_type(8)));
typedef float f32x4 __attribute__((ext_vector_type(4)));

#define MFMA(a,b,c) __builtin_amdgcn_mfma_f32_16x16x32_bf16(a,b,c,0,0,0)

__device__ __forceinline__ float sigm(float x){ return 1.0f/(1.0f+__expf(-x)); }
__device__ __forceinline__ float tanhfast(float x){ return 2.0f/(1.0f+__expf(-2.0f*x)) - 1.0f; }
__device__ __forceinline__ unsigned short f2bf(float x){
  unsigned u = __float_as_uint(x);
  u += 0x7FFFu + ((u>>16)&1u);
  return (unsigned short)(u>>16);
}
__device__ __forceinline__ float bf2f(unsigned short h){
  return __uint_as_float(((unsigned)h)<<16);
}

union bfu { bf16x8 v; unsigned u[4]; unsigned short s[8]; };

// split 8 floats -> hi bf16x8 + lo bf16x8 (lo = rne(x - f32(hi))) — pure C, RNE
__device__ __forceinline__ void split8(const float* x, bfu& H, bfu& L){
  #pragma unroll
  for (int i = 0; i < 8; ++i){
    const unsigned short hh = f2bf(x[i]);
    H.s[i] = hh;
    L.s[i] = f2bf(x[i] - bf2f(hh));
  }
}

// ---------------- precompute kernels ----------------

__global__ __launch_bounds__(64)
void k_mlp(const float* __restrict__ Pplm,
           const float* __restrict__ Ws1, const float* __restrict__ bs1,
           const float* __restrict__ Ws2, const float* __restrict__ bs2,
           const float* __restrict__ Wg1, const float* __restrict__ bg1,
           const float* __restrict__ Wg2, const float* __restrict__ bg2,
           float* __restrict__ vv_ws, float* __restrict__ gn_ws)
{
  __shared__ float sH[64], sG[64], sgv[8];
  const int v = blockIdx.x, j = threadIdx.x;
  float a = bs1[j], g = bg1[j];
  for (int k = 0; k < 768; ++k){
    const float p = Pplm[v*768 + k];
    a = fmaf(p, Ws1[k*64 + j], a);
    g = fmaf(p, Wg1[k*64 + j], g);
  }
  sH[j] = fmaxf(a, 0.f);
  sG[j] = fmaxf(g, 0.f);
  __syncthreads();
  if (j < 5){
    float acc = bs2[j];
    for (int k = 0; k < 64; ++k) acc = fmaf(sH[k], Ws2[k*5 + j], acc);
    vv_ws[v*5 + j] = acc;
  }
  if (j < 8){
    float acc = bg2[j];
    for (int k = 0; k < 64; ++k) acc = fmaf(sG[k], Wg2[k*8 + j], acc);
    sgv[j] = acc;
  }
  __syncthreads();
  if (j == 0){
    float n = 0.f;
    for (int e = 0; e < 8; ++e) n += sgv[e]*sgv[e];
    n = fmaxf(sqrtf(n), 1e-12f);
    for (int e = 0; e < 8; ++e) gn_ws[v*8 + e] = sgv[e]/n;
  }
}

__global__ __launch_bounds__(64)
void k_adj(const float* __restrict__ gn_ws, float* __restrict__ adj_ws)
{
  const int v = blockIdx.x, j = threadIdx.x;
  float sc = 0.f;
  #pragma unroll
  for (int e = 0; e < 8; ++e) sc += gn_ws[v*8+e]*gn_ws[j*8+e];
  float mx = sc;
  for (int off = 32; off > 0; off >>= 1) mx = fmaxf(mx, __shfl_xor(mx, off));
  const float ex = __expf(sc - mx);
  float sm = ex;
  for (int off = 32; off > 0; off >>= 1) sm += __shfl_xor(sm, off);
  adj_ws[v*64 + j] = ex / sm;
}

__global__ __launch_bounds__(256)
void k_vto(const float* __restrict__ P, float* __restrict__ vto_ws)
{
  const int idx = blockIdx.x*256 + threadIdx.x;
  if (idx >= BB*VV) return;
  const int b = idx/VV, v = idx%VV;
  float s = 0.f;
  for (int t = 0; t < TT; ++t) s += P[((size_t)(b*TT+t))*128 + 64 + v];
  vto_ws[idx] = s;
}

// pack gate weights into per-lane MFMA B-fragments (bf16) + side tables
// frag id f = ((e*2 + kt)*2 + p); element (f*64 + lane)*8 + j
// ALL gates use K-order [x(0..31) | h(0..31)] with rarity (orig k=32) as side:
//   k' = kt*32 + (lane>>4)*8 + j ; orig_k = (k'<32) ? k' : k'+1
__global__ __launch_bounds__(256)
void k_bpack(const float* __restrict__ Wr, const float* __restrict__ br,
             const float* __restrict__ Wu, const float* __restrict__ bu,
             const float* __restrict__ Wc, const float* __restrict__ bc,
             unsigned short* __restrict__ Bru, unsigned short* __restrict__ Bcn,
             float* __restrict__ sideRU, float* __restrict__ sideC)
{
  const int idx = blockIdx.x*256 + threadIdx.x;
  if (idx < 20480){
    const int f = idx >> 9, rem = idx & 511, l = rem >> 3, j = rem & 7;
    const int p = f & 1, kt = (f>>1)&1, e = f>>2;
    const int kp = kt*32 + (l>>4)*8 + j;
    const int k = (kp < 32) ? kp : kp + 1;
    const int o = p*16 + (l&15);
    const int q = (e < 5) ? e : e - 5;
    const float* W = (e < 5) ? Wr : Wu;
    Bru[idx] = f2bf(W[(q*65 + k)*32 + o]);
  } else if (idx < 30720){
    const int i2 = idx - 20480;
    const int f = i2 >> 9, rem = i2 & 511, l = rem >> 3, j = rem & 7;
    const int p = f & 1, kt = (f>>1)&1, e = f>>2;
    const int kp = kt*32 + (l>>4)*8 + j;
    const int k = (kp < 32) ? kp : kp + 1;
    const int o = p*16 + (l&15);
    Bcn[i2] = f2bf(Wc[(e*65 + k)*32 + o]);
  } else if (idx < 31360){
    const int i3 = idx - 30720;            // [e:10][s:2][o:32]
    const int e = i3 >> 6, s = (i3 >> 5) & 1, o = i3 & 31;
    const int q = (e < 5) ? e : e - 5;
    float v;
    if (s == 0) v = (e < 5) ? Wr[(q*65 + 32)*32 + o] : Wu[(q*65 + 32)*32 + o]; // rarity weight
    else        v = (e < 5) ? br[q*32 + o] : bu[q*32 + o];
    sideRU[i3] = v;
  } else if (idx < 31680){
    const int i4 = idx - 31360;            // [e:5][s:2][o:32]
    const int e = i4 >> 6, s = (i4 >> 5) & 1, o = i4 & 31;
    sideC[i4] = s ? bc[e*32 + o] : Wc[(e*65 + 32)*32 + o];   // s=0: rarity weight
  }
}

// ---------------- main recurrent kernel: 1 block (256 thr / 4 waves) per batch ----------------

__global__ __launch_bounds__(256, 1)
void tedgn_main(const float* __restrict__ P, const float* __restrict__ Pstatic,
                const float* __restrict__ Pavg, const int* __restrict__ Plen,
                const float* __restrict__ Ptime,
                const float* __restrict__ w_val, const float* __restrict__ b_val,
                const float* __restrict__ w_per, const float* __restrict__ b_per,
                const float* __restrict__ w_lin, const float* __restrict__ b_lin,
                const float* __restrict__ emb1, const float* __restrict__ rarW,
                const float* __restrict__ Wse, const float* __restrict__ bse,
                const float* __restrict__ Wc1, const float* __restrict__ bc1,
                const float* __restrict__ Wc2, const float* __restrict__ bc2,
                const float* __restrict__ vv_ws, const float* __restrict__ adjb_ws,
                const float* __restrict__ vto_ws,
                const unsigned short* __restrict__ Bru_ws,
                const unsigned short* __restrict__ Bc_ws,
                const float* __restrict__ sideRU_ws, const float* __restrict__ sideC_ws,
                float* __restrict__ out)
{
  // XH^T double-buffered: [buf][hi/lo][feature 0..63 = x(32)|h(32)][v 0..79 pad]
  __shared__ __align__(16) unsigned short B0T[2][2][64][80];
  __shared__ __align__(16) unsigned short s_Wru[20480];   // gate weight B-fragments
  __shared__ __align__(16) unsigned short s_Wc[10240];
  __shared__ __align__(16) float A1f[4][16][68];   // per-wave comb rows (f32); col 64 = comb_rar
  __shared__ __align__(16) float hrF[4][16][36];   // per-wave h_r rows (f32)
  __shared__ __align__(16) float s_rar[2][64];
  __shared__ __align__(16) float s_m[2][64];
  __shared__ float s_sru[640], s_scd[320];
  __shared__ float s_outf[64][33];
  __shared__ float s_feat[128], s_hid[200];

  const int tid  = threadIdx.x;
  const int lane = tid & 63;
  const int wid  = tid >> 6;      // 4 waves; wave owns rows R..R+15
  const int l15  = lane & 15;
  const int l16g = lane >> 4;
  const int kgo  = l16g * 8;
  const int R    = wid * 16;
  const int v_own = R + l15;
  const int b    = blockIdx.x;
  const int len  = Plen[b];

  // LDS fills: side tables + weight fragments
  for (int i = tid; i < 640; i += 256) s_sru[i] = sideRU_ws[i];
  for (int i = tid; i < 320; i += 256) s_scd[i] = sideC_ws[i];
  {
    const uint4* src1 = (const uint4*)Bru_ws;
    uint4* dst1 = (uint4*)s_Wru;
    for (int i = tid; i < 2560; i += 256) dst1[i] = src1[i];
    const uint4* src2 = (const uint4*)Bc_ws;
    uint4* dst2 = (uint4*)s_Wc;
    for (int i = tid; i < 1280; i += 256) dst2[i] = src2[i];
  }

  // per-lane constants
  float adjb_r[2][8], rarW_r[2][8];
  #pragma unroll
  for (int kt = 0; kt < 2; ++kt)
    #pragma unroll
    for (int j = 0; j < 8; ++j){
      adjb_r[kt][j] = adjb_ws[v_own*64 + kt*32 + kgo + j];
      rarW_r[kt][j] = rarW   [v_own*64 + kt*32 + kgo + j];
    }
  float embr[8], wvr[8], bvr[8], wpr[8], bpr[8];
  #pragma unroll
  for (int j = 0; j < 8; ++j){
    const int d = kgo + j;
    embr[j] = emb1[v_own*DD + d];
    wvr[j]  = w_val[d];
    bvr[j]  = b_val[d];
    wpr[j]  = (d == 0) ? w_lin[0] : w_per[d-1];
    bpr[j]  = (d == 0) ? b_lin[0] : b_per[d-1];
  }
  float vvr[4][NQ];
  #pragma unroll
  for (int j = 0; j < 4; ++j)
    #pragma unroll
    for (int q = 0; q < NQ; ++q)
      vvr[j][q] = vv_ws[(R + l16g*4 + j)*NQ + q];
  const float vto_own = vto_ws[b*VV + v_own];

  float h[2][4]    = {{0.f,0.f,0.f,0.f},{0.f,0.f,0.f,0.f}};
  float outr[2][4] = {{0.f,0.f,0.f,0.f},{0.f,0.f,0.f,0.f}};
  bfu xfH, xfL;
  float rar_own, m_own;

  // ---- prologue: build step-0 state into buf 0 ----
  {
    const float pd = P[(size_t)(b*TT)*128 + v_own];
    const float pm = P[(size_t)(b*TT)*128 + 64 + v_own];
    const float pa = Pavg[(size_t)(b*TT)*VV + v_own];
    const float pt = Ptime[b*TT];
    const float rar_n = 0.5f * tanhfast(pa / (vto_own + 1.f));
    float xv[8];
    #pragma unroll
    for (int j = 0; j < 8; ++j){
      const int d = kgo + j;
      const float tearg = fmaf(pt, wpr[j], bpr[j]);
      const float te = (d == 0) ? tearg : __sinf(tearg);
      const float ve = fmaxf(fmaf(pd, wvr[j], bvr[j]), 0.f);
      xv[j] = (ve + te + embr[j]) * pm;
    }
    split8(xv, xfH, xfL);
    #pragma unroll
    for (int j = 0; j < 8; ++j){
      B0T[0][0][kgo + j][v_own] = xfH.s[j];
      B0T[0][1][kgo + j][v_own] = xfL.s[j];
    }
    // zero h feature rows (32..63) of buf 0
    *(uint2*)&B0T[0][0][32 + l15][R + l16g*4] = make_uint2(0u, 0u);
    *(uint2*)&B0T[0][1][32 + l15][R + l16g*4] = make_uint2(0u, 0u);
    *(uint2*)&B0T[0][0][48 + l15][R + l16g*4] = make_uint2(0u, 0u);
    *(uint2*)&B0T[0][1][48 + l15][R + l16g*4] = make_uint2(0u, 0u);
    if (l16g == 0){
      s_rar[0][v_own] = rar_n;
      s_m[0][v_own]   = pm;
    }
    rar_own = rar_n;
    m_own   = pm;
  }
  __syncthreads();

  #pragma clang loop unroll(disable)
  for (int t = 0; t < TT; ++t){
    const int cur = t & 1, nxt = cur ^ 1;

    // prefetch t+1 (consumed in tail)
    float pd = 0.f, pm = 0.f, pa = 0.f, pt = 0.f;
    const bool more = (t + 1 < TT);
    if (more){
      pd = P[(size_t)(b*TT + t + 1)*128 + v_own];
      pm = P[(size_t)(b*TT + t + 1)*128 + 64 + v_own];
      pa = Pavg[(size_t)(b*TT + t + 1)*VV + v_own];
      pt = Ptime[b*TT + t + 1];
    }

    // ---- adj A-fragments (in-register) + comb_rar partial ----
    bfu aAh[2], aAl[2];
    float crar = 0.f;
    #pragma unroll
    for (int kt = 0; kt < 2; ++kt){
      const float4 r0 = *(const float4*)&s_rar[cur][kt*32 + kgo];
      const float4 r1 = *(const float4*)&s_rar[cur][kt*32 + kgo + 4];
      const float4 m0 = *(const float4*)&s_m[cur][kt*32 + kgo];
      const float4 m1 = *(const float4*)&s_m[cur][kt*32 + kgo + 4];
      const float rj[8] = {r0.x,r0.y,r0.z,r0.w,r1.x,r1.y,r1.z,r1.w};
      const float mj[8] = {m0.x,m0.y,m0.z,m0.w,m1.x,m1.y,m1.z,m1.w};
      float av[8];
      #pragma unroll
      for (int j = 0; j < 8; ++j){
        const int k = kt*32 + kgo + j;
        const float e1 = fmaf(-rarW_r[kt][j], fabsf(rar_own - rj[j]), 1.0f);
        const float a  = adjb_r[kt][j] * e1 * (m_own * mj[j]);
        av[j] = (k == v_own) ? 1.0f : a;
        crar = fmaf(av[j], rj[j], crar);
      }
      split8(av, aAh[kt], aAl[kt]);
    }
    crar += __shfl_xor(crar, 16);
    crar += __shfl_xor(crar, 32);
    if (l16g == 0) A1f[wid][l15][64] = crar;

    // ---- comb = cur_adj @ XH64 (3-product hi/lo) -> A1f (f32, wave-private) ----
    #pragma unroll
    for (int n = 0; n < 4; ++n){
      f32x4 acc = {0.f,0.f,0.f,0.f};
      #pragma unroll
      for (int kt = 0; kt < 2; ++kt){
        const bf16x8 bh = *(const bf16x8*)&B0T[cur][0][n*16 + l15][kt*32 + kgo];
        const bf16x8 bl = *(const bf16x8*)&B0T[cur][1][n*16 + l15][kt*32 + kgo];
        acc = MFMA(aAh[kt].v, bh, acc);
        acc = MFMA(aAl[kt].v, bh, acc);
        acc = MFMA(aAh[kt].v, bl, acc);
      }
      const int col = n*16 + l15;
      #pragma unroll
      for (int j = 0; j < 4; ++j) A1f[wid][l16g*4 + j][col] = acc[j];
    }
    __builtin_amdgcn_sched_barrier(0);   // keep A1f stores before the reads below

    // ---- gate A-fragments from comb (same-wave LDS round trip) ----
    bfu aH[2], aL[2];
    #pragma unroll
    for (int kt = 0; kt < 2; ++kt){
      float xv[8];
      *(float4*)&xv[0] = *(const float4*)&A1f[wid][l15][kt*32 + kgo];
      *(float4*)&xv[4] = *(const float4*)&A1f[wid][l15][kt*32 + kgo + 4];
      split8(xv, aH[kt], aL[kt]);
    }
    float a64f[4];
    #pragma unroll
    for (int j = 0; j < 4; ++j) a64f[j] = A1f[wid][l16g*4 + j][64];

    // ---- r gates ----
    float hr[2][4];
    {
      f32x4 ag[5][2];
      #pragma unroll
      for (int e = 0; e < 5; ++e)
        #pragma unroll
        for (int p2 = 0; p2 < 2; ++p2){
          const int o = p2*16 + l15;
          const float w64 = s_sru[e*64 + o];
          const float bs  = s_sru[e*64 + 32 + o];
          #pragma unroll
          for (int j = 0; j < 4; ++j) ag[e][p2][j] = fmaf(a64f[j], w64, bs);
        }
      #pragma unroll
      for (int e = 0; e < 5; ++e)
        #pragma unroll
        for (int p2 = 0; p2 < 2; ++p2){
          const bf16x8 w0 = *(const bf16x8*)&s_Wru[(((e*2+0)*2+p2)*64 + lane)*8];
          const bf16x8 w1 = *(const bf16x8*)&s_Wru[(((e*2+1)*2+p2)*64 + lane)*8];
          ag[e][p2] = MFMA(aH[0].v, w0, ag[e][p2]);
          ag[e][p2] = MFMA(aL[0].v, w0, ag[e][p2]);
          ag[e][p2] = MFMA(aH[1].v, w1, ag[e][p2]);
          ag[e][p2] = MFMA(aL[1].v, w1, ag[e][p2]);
        }
      #pragma unroll
      for (int p2 = 0; p2 < 2; ++p2)
        #pragma unroll
        for (int j = 0; j < 4; ++j){
          const float pr = vvr[j][0]*ag[0][p2][j] + vvr[j][1]*ag[1][p2][j]
                         + vvr[j][2]*ag[2][p2][j] + vvr[j][3]*ag[3][p2][j]
                         + vvr[j][4]*ag[4][p2][j];
          hr[p2][j] = sigm(pr) * h[p2][j];
          hrF[wid][l16g*4 + j][p2*16 + l15] = hr[p2][j];
        }
    }
    __builtin_amdgcn_sched_barrier(0);   // keep hrF stores before cand reads

    // ---- u gates ----
    float uu[2][4];
    {
      f32x4 ag[5][2];
      #pragma unroll
      for (int e = 0; e < 5; ++e)
        #pragma unroll
        for (int p2 = 0; p2 < 2; ++p2){
          const int o = p2*16 + l15;
          const float w64 = s_sru[(5 + e)*64 + o];
          const float bs  = s_sru[(5 + e)*64 + 32 + o];
          #pragma unroll
          for (int j = 0; j < 4; ++j) ag[e][p2][j] = fmaf(a64f[j], w64, bs);
        }
      #pragma unroll
      for (int e = 0; e < 5; ++e)
        #pragma unroll
        for (int p2 = 0; p2 < 2; ++p2){
          const bf16x8 w0 = *(const bf16x8*)&s_Wru[((((5+e)*2+0)*2+p2)*64 + lane)*8];
          const bf16x8 w1 = *(const bf16x8*)&s_Wru[((((5+e)*2+1)*2+p2)*64 + lane)*8];
          ag[e][p2] = MFMA(aH[0].v, w0, ag[e][p2]);
          ag[e][p2] = MFMA(aL[0].v, w0, ag[e][p2]);
          ag[e][p2] = MFMA(aH[1].v, w1, ag[e][p2]);
          ag[e][p2] = MFMA(aL[1].v, w1, ag[e][p2]);
        }
      #pragma unroll
      for (int p2 = 0; p2 < 2; ++p2)
        #pragma unroll
        for (int j = 0; j < 4; ++j){
          const float pu = vvr[j][0]*ag[0][p2][j] + vvr[j][1]*ag[1][p2][j]
                         + vvr[j][2]*ag[2][p2][j] + vvr[j][3]*ag[3][p2][j]
                         + vvr[j][4]*ag[4][p2][j];
          uu[p2][j] = sigm(pu);
        }
    }

    // ---- cand + GRU update ----
    {
      bfu hH, hL;
      {
        float hv[8];
        *(float4*)&hv[0] = *(const float4*)&hrF[wid][l15][kgo];
        *(float4*)&hv[4] = *(const float4*)&hrF[wid][l15][kgo + 4];
        split8(hv, hH, hL);
      }
      float rar_cj[4], m_cj[4];
      #pragma unroll
      for (int j = 0; j < 4; ++j){
        rar_cj[j] = s_rar[cur][R + l16g*4 + j];
        m_cj[j]   = s_m[cur][R + l16g*4 + j];
      }
      f32x4 ag[5][2];
      #pragma unroll
      for (int e = 0; e < 5; ++e)
        #pragma unroll
        for (int p2 = 0; p2 < 2; ++p2){
          const int o = p2*16 + l15;
          const float w32 = s_scd[e*64 + o];
          const float bs  = s_scd[e*64 + 32 + o];
          #pragma unroll
          for (int j = 0; j < 4; ++j) ag[e][p2][j] = fmaf(rar_cj[j], w32, bs);
        }
      #pragma unroll
      for (int e = 0; e < 5; ++e)
        #pragma unroll
        for (int p2 = 0; p2 < 2; ++p2){
          const bf16x8 w0 = *(const bf16x8*)&s_Wc[(((e*2+0)*2+p2)*64 + lane)*8];
          const bf16x8 w1 = *(const bf16x8*)&s_Wc[(((e*2+1)*2+p2)*64 + lane)*8];
          ag[e][p2] = MFMA(xfH.v, w0, ag[e][p2]);
          ag[e][p2] = MFMA(xfL.v, w0, ag[e][p2]);
          ag[e][p2] = MFMA(hH.v,  w1, ag[e][p2]);
          ag[e][p2] = MFMA(hL.v,  w1, ag[e][p2]);
        }
      const bool snap = (t == len - 1);
      #pragma unroll
      for (int p2 = 0; p2 < 2; ++p2)
        #pragma unroll
        for (int j = 0; j < 4; ++j){
          const float pc = vvr[j][0]*ag[0][p2][j] + vvr[j][1]*ag[1][p2][j]
                         + vvr[j][2]*ag[2][p2][j] + vvr[j][3]*ag[3][p2][j]
                         + vvr[j][4]*ag[4][p2][j];
          const float cd = tanhfast(pc);
          const float hn = fmaf(uu[p2][j], cd - hr[p2][j], hr[p2][j]);
          const float hf = (m_cj[j] > 0.5f) ? hn : h[p2][j];
          h[p2][j] = hf;
          if (snap) outr[p2][j] = hf;
        }
    }

    // ---- write h to B0T[nxt] feature rows 32..63 ----
    {
      float h8[8] = {h[0][0],h[0][1],h[0][2],h[0][3],h[1][0],h[1][1],h[1][2],h[1][3]};
      bfu HH, HL;
      split8(h8, HH, HL);
      *(uint2*)&B0T[nxt][0][32 + l15][R + l16g*4] = make_uint2(HH.u[0], HH.u[1]);
      *(uint2*)&B0T[nxt][1][32 + l15][R + l16g*4] = make_uint2(HL.u[0], HL.u[1]);
      *(uint2*)&B0T[nxt][0][48 + l15][R + l16g*4] = make_uint2(HH.u[2], HH.u[3]);
      *(uint2*)&B0T[nxt][1][48 + l15][R + l16g*4] = make_uint2(HL.u[2], HL.u[3]);
    }

    // ---- next-step x / rar / tables into buf nxt ----
    if (more){
      const float rar_n = 0.5f * tanhfast(pa / (vto_own + 1.f));
      float xv[8];
      #pragma unroll
      for (int j = 0; j < 8; ++j){
        const int d = kgo + j;
        const float tearg = fmaf(pt, wpr[j], bpr[j]);
        const float te = (d == 0) ? tearg : __sinf(tearg);
        const float ve = fmaxf(fmaf(pd, wvr[j], bvr[j]), 0.f);
        xv[j] = (ve + te + embr[j]) * pm;
      }
      split8(xv, xfH, xfL);
      #pragma unroll
      for (int j = 0; j < 8; ++j){
        B0T[nxt][0][kgo + j][v_own] = xfH.s[j];
        B0T[nxt][1][kgo + j][v_own] = xfL.s[j];
      }
      if (l16g == 0){
        s_rar[nxt][v_own] = rar_n;
        s_m[nxt][v_own]   = pm;
      }
      rar_own = rar_n;
      m_own   = pm;
    }
    __syncthreads();
  }

  // ---- epilogue: feat -> 200-unit MLP -> 2 logits ----
  #pragma unroll
  for (int p2 = 0; p2 < 2; ++p2)
    #pragma unroll
    for (int j = 0; j < 4; ++j)
      s_outf[R + l16g*4 + j][p2*16 + l15] = outr[p2][j];
  __syncthreads();
  if (tid < VV){
    float s = 0.f;
    #pragma unroll
    for (int d = 0; d < DD; ++d) s += s_outf[tid][d];
    s_feat[tid] = s;
  } else if (tid < 2*VV){
    const int v = tid - VV;
    float se = bse[v];
    #pragma unroll
    for (int k = 0; k < 16; ++k) se = fmaf(Pstatic[b*16 + k], Wse[k*VV + v], se);
    s_feat[VV + v] = se;
  }
  __syncthreads();
  if (tid < 200){
    float a = bc1[tid];
    for (int k = 0; k < 128; ++k) a = fmaf(s_feat[k], Wc1[k*200 + tid], a);
    s_hid[tid] = fmaxf(a, 0.f);
  }
  __syncthreads();
  if (tid < 2){
    float a = bc2[tid];
    for (int k = 0; k < 200; ++k) a = fmaf(s_hid[k], Wc2[k*2 + tid], a);
    out[b*2 + tid] = a;
  }
}

// ---------------- launch ----------------

extern "C" void kernel_launch(void* const* d_in, const int* in_sizes, int n_in,
                              void* d_out, int out_size, void* d_ws, size_t ws_size,
                              hipStream_t stream) {
  (void)in_sizes; (void)n_in; (void)out_size; (void)ws_size;
  const float* P       = (const float*)d_in[0];
  const float* Pstatic = (const float*)d_in[1];
  const float* Pavg    = (const float*)d_in[2];
  const int*   Plen    = (const int*)  d_in[3];
  const float* Ptime   = (const float*)d_in[4];
  const float* Pplm    = (const float*)d_in[5];
  const float* w_val   = (const float*)d_in[6];
  const float* b_val   = (const float*)d_in[7];
  const float* w_per   = (const float*)d_in[8];
  const float* b_per   = (const float*)d_in[9];
  const float* w_lin   = (const float*)d_in[10];
  const float* b_lin   = (const float*)d_in[11];
  const float* emb1    = (const float*)d_in[12];
  const float* Ws1     = (const float*)d_in[13];
  const float* bs1     = (const float*)d_in[14];
  const float* Ws2     = (const float*)d_in[15];
  const float* bs2     = (const float*)d_in[16];
  const float* Wg1     = (const float*)d_in[17];
  const float* bg1     = (const float*)d_in[18];
  const float* Wg2     = (const float*)d_in[19];
  const float* bg2     = (const float*)d_in[20];
  const float* rarW    = (const float*)d_in[21];
  const float* Wu      = (const float*)d_in[22];
  const float* bu      = (const float*)d_in[23];
  const float* Wr      = (const float*)d_in[24];
  const float* br      = (const float*)d_in[25];
  const float* Wcand   = (const float*)d_in[26];
  const float* bcand   = (const float*)d_in[27];
  const float* Wse     = (const float*)d_in[28];
  const float* bse     = (const float*)d_in[29];
  const float* Wc1     = (const float*)d_in[30];
  const float* bc1     = (const float*)d_in[31];
  const float* Wc2     = (const float*)d_in[32];
  const float* bc2     = (const float*)d_in[33];

  float* ws = (float*)d_ws;
  float*          vv_ws   = ws;                 // 320 f
  float*          gn_ws   = ws + 320;           // 512 f
  float*          adjb_ws = ws + 832;           // 4096 f
  float*          vto_ws  = ws + 4928;          // 8192 f
  unsigned short* Bru_ws  = (unsigned short*)(ws + 13120);   // 20480 u16
  unsigned short* Bc_ws   = (unsigned short*)(ws + 23360);   // 10240 u16
  float*          sideRU_ws = ws + 28480;       // 640 f
  float*          sideC_ws  = ws + 29120;       // 320 f

  k_mlp  <<<64, 64, 0, stream>>>(Pplm, Ws1, bs1, Ws2, bs2, Wg1, bg1, Wg2, bg2, vv_ws, gn_ws);
  k_adj  <<<64, 64, 0, stream>>>(gn_ws, adjb_ws);
  k_vto  <<<(BB*VV + 255)/256, 256, 0, stream>>>(P, vto_ws);
  k_bpack<<<124, 256, 0, stream>>>(Wr, br, Wu, bu, Wcand, bcand, Bru_ws, Bc_ws, sideRU_ws, sideC_ws);

  tedgn_main<<<BB, 256, 0, stream>>>(P, Pstatic, Pavg, Plen, Ptime,
                                     w_val, b_val, w_per, b_per, w_lin, b_lin,
                                     emb1, rarW, Wse, bse, Wc1, bc1, Wc2, bc2,
                                     vv_ws, adjb_ws, vto_ws,
                                     Bru_ws, Bc_ws, sideRU_ws, sideC_ws,
                                     (float*)d_out);
}

// Round 8
// 623.443 us; speedup vs baseline: 12.7074x; 1.0598x over previous
//
#include <hip/hip_runtime.h>
#include <hip/hip_bf16.h>
#include <math.h>

#define BB 128
#define TT 128
#define VV 64
#define DD 32
#define NQ 5

typedef short bf16x8 __attribute__((ext_vector_type(8)));
typedef float f32x4 __attribute__((ext_vector_type(4)));

#define MFMA(a,b,c) __builtin_amdgcn_mfma_f32_16x16x32_bf16(a,b,c,0,0,0)
// sched_barrier mask: allow ALU|VALU|SALU|MFMA|VMEM* to cross; block DS ops
#define SB_DS() __builtin_amdgcn_sched_barrier(0x7F)

__device__ __forceinline__ float sigm(float x){ return 1.0f/(1.0f+__expf(-x)); }
__device__ __forceinline__ float tanhfast(float x){ return 2.0f/(1.0f+__expf(-2.0f*x)) - 1.0f; }
__device__ __forceinline__ unsigned short f2bf(float x){
  unsigned u = __float_as_uint(x);
  u += 0x7FFFu + ((u>>16)&1u);
  return (unsigned short)(u>>16);
}
__device__ __forceinline__ float bf2f(unsigned short h){
  return __uint_as_float(((unsigned)h)<<16);
}

union bfu { bf16x8 v; unsigned u[4]; unsigned short s[8]; };

// split 8 floats -> hi bf16x8 + lo bf16x8 (lo = rne(x - f32(hi))) via cvt_pk (RNE)
__device__ __forceinline__ void split8(const float* x, bfu& H, bfu& L){
  #pragma unroll
  for (int i = 0; i < 4; ++i){
    const float a = x[2*i], c = x[2*i+1];
    const __hip_bfloat162 hp = __float22bfloat162_rn(make_float2(a, c));
    unsigned hu; __builtin_memcpy(&hu, &hp, 4);
    H.u[i] = hu;
    const float ah = __uint_as_float(hu << 16);
    const float ch = __uint_as_float(hu & 0xFFFF0000u);
    const __hip_bfloat162 lp = __float22bfloat162_rn(make_float2(a - ah, c - ch));
    unsigned lu; __builtin_memcpy(&lu, &lp, 4);
    L.u[i] = lu;
  }
}

// ---------------- precompute kernels ----------------

__global__ __launch_bounds__(64)
void k_mlp(const float* __restrict__ Pplm,
           const float* __restrict__ Ws1, const float* __restrict__ bs1,
           const float* __restrict__ Ws2, const float* __restrict__ bs2,
           const float* __restrict__ Wg1, const float* __restrict__ bg1,
           const float* __restrict__ Wg2, const float* __restrict__ bg2,
           float* __restrict__ vv_ws, float* __restrict__ gn_ws)
{
  __shared__ float sH[64], sG[64], sgv[8];
  const int v = blockIdx.x, j = threadIdx.x;
  float a = bs1[j], g = bg1[j];
  for (int k = 0; k < 768; ++k){
    const float p = Pplm[v*768 + k];
    a = fmaf(p, Ws1[k*64 + j], a);
    g = fmaf(p, Wg1[k*64 + j], g);
  }
  sH[j] = fmaxf(a, 0.f);
  sG[j] = fmaxf(g, 0.f);
  __syncthreads();
  if (j < 5){
    float acc = bs2[j];
    for (int k = 0; k < 64; ++k) acc = fmaf(sH[k], Ws2[k*5 + j], acc);
    vv_ws[v*5 + j] = acc;
  }
  if (j < 8){
    float acc = bg2[j];
    for (int k = 0; k < 64; ++k) acc = fmaf(sG[k], Wg2[k*8 + j], acc);
    sgv[j] = acc;
  }
  __syncthreads();
  if (j == 0){
    float n = 0.f;
    for (int e = 0; e < 8; ++e) n += sgv[e]*sgv[e];
    n = fmaxf(sqrtf(n), 1e-12f);
    for (int e = 0; e < 8; ++e) gn_ws[v*8 + e] = sgv[e]/n;
  }
}

__global__ __launch_bounds__(64)
void k_adj(const float* __restrict__ gn_ws, float* __restrict__ adj_ws)
{
  const int v = blockIdx.x, j = threadIdx.x;
  float sc = 0.f;
  #pragma unroll
  for (int e = 0; e < 8; ++e) sc += gn_ws[v*8+e]*gn_ws[j*8+e];
  float mx = sc;
  for (int off = 32; off > 0; off >>= 1) mx = fmaxf(mx, __shfl_xor(mx, off));
  const float ex = __expf(sc - mx);
  float sm = ex;
  for (int off = 32; off > 0; off >>= 1) sm += __shfl_xor(sm, off);
  adj_ws[v*64 + j] = ex / sm;
}

__global__ __launch_bounds__(256)
void k_vto(const float* __restrict__ P, float* __restrict__ vto_ws)
{
  const int idx = blockIdx.x*256 + threadIdx.x;
  if (idx >= BB*VV) return;
  const int b = idx/VV, v = idx%VV;
  float s = 0.f;
  for (int t = 0; t < TT; ++t) s += P[((size_t)(b*TT+t))*128 + 64 + v];
  vto_ws[idx] = s;
}

// pack gate weights into per-lane MFMA B-fragments (bf16) + paired side tables
// frag id f = ((e*2 + kt)*2 + p); element (f*64 + lane)*8 + j
// ALL gates use K-order [x(0..31) | h(0..31)] with rarity (orig k=32) as side:
//   k' = kt*32 + (lane>>4)*8 + j ; orig_k = (k'<32) ? k' : k'+1
// side tables: [e][o][2] pairs -> {rarity weight, bias}
__global__ __launch_bounds__(256)
void k_bpack(const float* __restrict__ Wr, const float* __restrict__ br,
             const float* __restrict__ Wu, const float* __restrict__ bu,
             const float* __restrict__ Wc, const float* __restrict__ bc,
             unsigned short* __restrict__ Bru, unsigned short* __restrict__ Bcn,
             float* __restrict__ sideRU, float* __restrict__ sideC)
{
  const int idx = blockIdx.x*256 + threadIdx.x;
  if (idx < 20480){
    const int f = idx >> 9, rem = idx & 511, l = rem >> 3, j = rem & 7;
    const int p = f & 1, kt = (f>>1)&1, e = f>>2;
    const int kp = kt*32 + (l>>4)*8 + j;
    const int k = (kp < 32) ? kp : kp + 1;
    const int o = p*16 + (l&15);
    const int q = (e < 5) ? e : e - 5;
    const float* W = (e < 5) ? Wr : Wu;
    Bru[idx] = f2bf(W[(q*65 + k)*32 + o]);
  } else if (idx < 30720){
    const int i2 = idx - 20480;
    const int f = i2 >> 9, rem = i2 & 511, l = rem >> 3, j = rem & 7;
    const int p = f & 1, kt = (f>>1)&1, e = f>>2;
    const int kp = kt*32 + (l>>4)*8 + j;
    const int k = (kp < 32) ? kp : kp + 1;
    const int o = p*16 + (l&15);
    Bcn[i2] = f2bf(Wc[(e*65 + k)*32 + o]);
  } else if (idx < 31360){
    const int i3 = idx - 30720;            // [e:10][o:32][s:2] pairs
    const int e = i3 >> 6, rem = i3 & 63, o = rem >> 1, s = rem & 1;
    const int q = (e < 5) ? e : e - 5;
    float v;
    if (s == 0) v = (e < 5) ? Wr[(q*65 + 32)*32 + o] : Wu[(q*65 + 32)*32 + o]; // rarity weight
    else        v = (e < 5) ? br[q*32 + o] : bu[q*32 + o];
    sideRU[i3] = v;
  } else if (idx < 31680){
    const int i4 = idx - 31360;            // [e:5][o:32][s:2] pairs
    const int e = i4 >> 6, rem = i4 & 63, o = rem >> 1, s = rem & 1;
    sideC[i4] = s ? bc[e*32 + o] : Wc[(e*65 + 32)*32 + o];   // s=0: rarity weight
  }
}

// ---------------- main recurrent kernel: 1 block (256 thr / 4 waves) per batch ----------------

__global__ __launch_bounds__(256, 1)
void tedgn_main(const float* __restrict__ P, const float* __restrict__ Pstatic,
                const float* __restrict__ Pavg, const int* __restrict__ Plen,
                const float* __restrict__ Ptime,
                const float* __restrict__ w_val, const float* __restrict__ b_val,
                const float* __restrict__ w_per, const float* __restrict__ b_per,
                const float* __restrict__ w_lin, const float* __restrict__ b_lin,
                const float* __restrict__ emb1, const float* __restrict__ rarW,
                const float* __restrict__ Wse, const float* __restrict__ bse,
                const float* __restrict__ Wc1, const float* __restrict__ bc1,
                const float* __restrict__ Wc2, const float* __restrict__ bc2,
                const float* __restrict__ vv_ws, const float* __restrict__ adjb_ws,
                const float* __restrict__ vto_ws,
                const unsigned short* __restrict__ Bru_ws,
                const unsigned short* __restrict__ Bc_ws,
                const float* __restrict__ sideRU_ws, const float* __restrict__ sideC_ws,
                float* __restrict__ out)
{
  // XH^T double-buffered: [buf][hi/lo][feature 0..63 = x(32)|h(32)][v, pad 72]
  __shared__ __align__(16) unsigned short B0T[2][2][64][72];
  __shared__ __align__(16) unsigned short s_Wru[20480];   // gate weight B-fragments
  __shared__ __align__(16) unsigned short s_Wc[10240];
  __shared__ __align__(16) float A1f[4][16][68];   // per-wave comb rows (f32); col 64 = comb_rar
  __shared__ __align__(16) float hrF[4][16][36];   // per-wave h_r rows (f32)
  __shared__ __align__(16) float s_rar[2][64];
  __shared__ __align__(16) float s_m[2][64];
  __shared__ float s_sru[640], s_scd[320];
  __shared__ float s_outf[64][33];
  __shared__ float s_feat[128], s_hid[200];

  const int tid  = threadIdx.x;
  const int lane = tid & 63;
  const int wid  = tid >> 6;      // 4 waves; wave owns rows R..R+15
  const int l15  = lane & 15;
  const int l16g = lane >> 4;
  const int kgo  = l16g * 8;
  const int R    = wid * 16;
  const int v_own = R + l15;
  const int b    = blockIdx.x;
  const int len  = Plen[b];

  // LDS fills: side tables + weight fragments
  for (int i = tid; i < 640; i += 256) s_sru[i] = sideRU_ws[i];
  for (int i = tid; i < 320; i += 256) s_scd[i] = sideC_ws[i];
  {
    const uint4* src1 = (const uint4*)Bru_ws;
    uint4* dst1 = (uint4*)s_Wru;
    for (int i = tid; i < 2560; i += 256) dst1[i] = src1[i];
    const uint4* src2 = (const uint4*)Bc_ws;
    uint4* dst2 = (uint4*)s_Wc;
    for (int i = tid; i < 1280; i += 256) dst2[i] = src2[i];
  }

  // per-lane constants
  float adjb_r[2][8], rarW_r[2][8];
  #pragma unroll
  for (int kt = 0; kt < 2; ++kt)
    #pragma unroll
    for (int j = 0; j < 8; ++j){
      adjb_r[kt][j] = adjb_ws[v_own*64 + kt*32 + kgo + j];
      rarW_r[kt][j] = rarW   [v_own*64 + kt*32 + kgo + j];
    }
  float embr[8], wvr[8], bvr[8], wpr[8], bpr[8];
  #pragma unroll
  for (int j = 0; j < 8; ++j){
    const int d = kgo + j;
    embr[j] = emb1[v_own*DD + d];
    wvr[j]  = w_val[d];
    bvr[j]  = b_val[d];
    wpr[j]  = (d == 0) ? w_lin[0] : w_per[d-1];
    bpr[j]  = (d == 0) ? b_lin[0] : b_per[d-1];
  }
  float vvr[4][NQ];
  #pragma unroll
  for (int j = 0; j < 4; ++j)
    #pragma unroll
    for (int q = 0; q < NQ; ++q)
      vvr[j][q] = vv_ws[(R + l16g*4 + j)*NQ + q];
  const float vto_own = vto_ws[b*VV + v_own];

  float h[2][4]    = {{0.f,0.f,0.f,0.f},{0.f,0.f,0.f,0.f}};
  float outr[2][4] = {{0.f,0.f,0.f,0.f},{0.f,0.f,0.f,0.f}};
  bfu xfH, xfL;
  float rar_own, m_own;

  // ---- prologue: build step-0 state into buf 0 ----
  {
    const float pd = P[(size_t)(b*TT)*128 + v_own];
    const float pm = P[(size_t)(b*TT)*128 + 64 + v_own];
    const float pa = Pavg[(size_t)(b*TT)*VV + v_own];
    const float pt = Ptime[b*TT];
    const float rar_n = 0.5f * tanhfast(pa / (vto_own + 1.f));
    float xv[8];
    #pragma unroll
    for (int j = 0; j < 8; ++j){
      const int d = kgo + j;
      const float tearg = fmaf(pt, wpr[j], bpr[j]);
      const float te = (d == 0) ? tearg : __sinf(tearg);
      const float ve = fmaxf(fmaf(pd, wvr[j], bvr[j]), 0.f);
      xv[j] = (ve + te + embr[j]) * pm;
    }
    split8(xv, xfH, xfL);
    #pragma unroll
    for (int j = 0; j < 8; ++j){
      B0T[0][0][kgo + j][v_own] = xfH.s[j];
      B0T[0][1][kgo + j][v_own] = xfL.s[j];
    }
    // zero h feature rows (32..63) of buf 0
    *(uint2*)&B0T[0][0][32 + l15][R + l16g*4] = make_uint2(0u, 0u);
    *(uint2*)&B0T[0][1][32 + l15][R + l16g*4] = make_uint2(0u, 0u);
    *(uint2*)&B0T[0][0][48 + l15][R + l16g*4] = make_uint2(0u, 0u);
    *(uint2*)&B0T[0][1][48 + l15][R + l16g*4] = make_uint2(0u, 0u);
    if (l16g == 0){
      s_rar[0][v_own] = rar_n;
      s_m[0][v_own]   = pm;
    }
    rar_own = rar_n;
    m_own   = pm;
  }
  __syncthreads();

  #pragma clang loop unroll(disable)
  for (int t = 0; t < TT; ++t){
    const int cur = t & 1, nxt = cur ^ 1;

    // prefetch t+1 (consumed in tail)
    float pd = 0.f, pm = 0.f, pa = 0.f, pt = 0.f;
    const bool more = (t + 1 < TT);
    if (more){
      pd = P[(size_t)(b*TT + t + 1)*128 + v_own];
      pm = P[(size_t)(b*TT + t + 1)*128 + 64 + v_own];
      pa = Pavg[(size_t)(b*TT + t + 1)*VV + v_own];
      pt = Ptime[b*TT + t + 1];
    }

    // ---- adj A-fragments (in-register) + comb_rar partial ----
    bfu aAh[2], aAl[2];
    float crar = 0.f;
    #pragma unroll
    for (int kt = 0; kt < 2; ++kt){
      const float4 r0 = *(const float4*)&s_rar[cur][kt*32 + kgo];
      const float4 r1 = *(const float4*)&s_rar[cur][kt*32 + kgo + 4];
      const float4 m0 = *(const float4*)&s_m[cur][kt*32 + kgo];
      const float4 m1 = *(const float4*)&s_m[cur][kt*32 + kgo + 4];
      const float rj[8] = {r0.x,r0.y,r0.z,r0.w,r1.x,r1.y,r1.z,r1.w};
      const float mj[8] = {m0.x,m0.y,m0.z,m0.w,m1.x,m1.y,m1.z,m1.w};
      float av[8];
      #pragma unroll
      for (int j = 0; j < 8; ++j){
        const int k = kt*32 + kgo + j;
        const float e1 = fmaf(-rarW_r[kt][j], fabsf(rar_own - rj[j]), 1.0f);
        const float a  = adjb_r[kt][j] * e1 * (m_own * mj[j]);
        av[j] = (k == v_own) ? 1.0f : a;
        crar = fmaf(av[j], rj[j], crar);
      }
      split8(av, aAh[kt], aAl[kt]);
    }
    crar += __shfl_xor(crar, 16);
    crar += __shfl_xor(crar, 32);
    if (l16g == 0) A1f[wid][l15][64] = crar;

    // ---- comb = cur_adj @ XH64 (3-product hi/lo) -> A1f (f32, wave-private) ----
    #pragma unroll
    for (int n = 0; n < 4; ++n){
      f32x4 acc = {0.f,0.f,0.f,0.f};
      #pragma unroll
      for (int kt = 0; kt < 2; ++kt){
        const bf16x8 bh = *(const bf16x8*)&B0T[cur][0][n*16 + l15][kt*32 + kgo];
        const bf16x8 bl = *(const bf16x8*)&B0T[cur][1][n*16 + l15][kt*32 + kgo];
        acc = MFMA(aAh[kt].v, bh, acc);
        acc = MFMA(aAl[kt].v, bh, acc);
        acc = MFMA(aAh[kt].v, bl, acc);
      }
      const int col = n*16 + l15;
      #pragma unroll
      for (int j = 0; j < 4; ++j) A1f[wid][l16g*4 + j][col] = acc[j];
    }
    SB_DS();   // keep A1f stores (DS) before the A1f reads below; VALU/MFMA free

    // ---- gate A-fragments from comb (same-wave LDS round trip) ----
    bfu aH[2], aL[2];
    #pragma unroll
    for (int kt = 0; kt < 2; ++kt){
      float xv[8];
      *(float4*)&xv[0] = *(const float4*)&A1f[wid][l15][kt*32 + kgo];
      *(float4*)&xv[4] = *(const float4*)&A1f[wid][l15][kt*32 + kgo + 4];
      split8(xv, aH[kt], aL[kt]);
    }
    float a64f[4];
    #pragma unroll
    for (int j = 0; j < 4; ++j) a64f[j] = A1f[wid][l16g*4 + j][64];

    // ---- r+u gates merged (20 independent MFMA chains) ----
    float hr[2][4], uu[2][4];
    {
      f32x4 ag[10][2];
      #pragma unroll
      for (int e = 0; e < 10; ++e)
        #pragma unroll
        for (int p2 = 0; p2 < 2; ++p2){
          const float2 wb = *(const float2*)&s_sru[e*64 + (p2*16 + l15)*2];
          #pragma unroll
          for (int j = 0; j < 4; ++j) ag[e][p2][j] = fmaf(a64f[j], wb.x, wb.y);
        }
      #pragma unroll
      for (int e = 0; e < 10; ++e)
        #pragma unroll
        for (int p2 = 0; p2 < 2; ++p2){
          const bf16x8 w0 = *(const bf16x8*)&s_Wru[(((e*2+0)*2+p2)*64 + lane)*8];
          const bf16x8 w1 = *(const bf16x8*)&s_Wru[(((e*2+1)*2+p2)*64 + lane)*8];
          ag[e][p2] = MFMA(aH[0].v, w0, ag[e][p2]);
          ag[e][p2] = MFMA(aL[0].v, w0, ag[e][p2]);
          ag[e][p2] = MFMA(aH[1].v, w1, ag[e][p2]);
          ag[e][p2] = MFMA(aL[1].v, w1, ag[e][p2]);
        }
      // r combine first -> hrF writes issue early
      #pragma unroll
      for (int p2 = 0; p2 < 2; ++p2)
        #pragma unroll
        for (int j = 0; j < 4; ++j){
          const float pr = vvr[j][0]*ag[0][p2][j] + vvr[j][1]*ag[1][p2][j]
                         + vvr[j][2]*ag[2][p2][j] + vvr[j][3]*ag[3][p2][j]
                         + vvr[j][4]*ag[4][p2][j];
          hr[p2][j] = sigm(pr) * h[p2][j];
          hrF[wid][l16g*4 + j][p2*16 + l15] = hr[p2][j];
        }
      #pragma unroll
      for (int p2 = 0; p2 < 2; ++p2)
        #pragma unroll
        for (int j = 0; j < 4; ++j){
          const float pu = vvr[j][0]*ag[5][p2][j] + vvr[j][1]*ag[6][p2][j]
                         + vvr[j][2]*ag[7][p2][j] + vvr[j][3]*ag[8][p2][j]
                         + vvr[j][4]*ag[9][p2][j];
          uu[p2][j] = sigm(pu);
        }
    }
    SB_DS();   // keep hrF stores (DS) before cand's hrF reads

    // ---- cand + GRU update ----
    {
      bfu hH, hL;
      {
        float hv[8];
        *(float4*)&hv[0] = *(const float4*)&hrF[wid][l15][kgo];
        *(float4*)&hv[4] = *(const float4*)&hrF[wid][l15][kgo + 4];
        split8(hv, hH, hL);
      }
      float rar_cj[4], m_cj[4];
      #pragma unroll
      for (int j = 0; j < 4; ++j){
        rar_cj[j] = s_rar[cur][R + l16g*4 + j];
        m_cj[j]   = s_m[cur][R + l16g*4 + j];
      }
      f32x4 ag[5][2];
      #pragma unroll
      for (int e = 0; e < 5; ++e)
        #pragma unroll
        for (int p2 = 0; p2 < 2; ++p2){
          const float2 wb = *(const float2*)&s_scd[e*64 + (p2*16 + l15)*2];
          #pragma unroll
          for (int j = 0; j < 4; ++j) ag[e][p2][j] = fmaf(rar_cj[j], wb.x, wb.y);
        }
      #pragma unroll
      for (int e = 0; e < 5; ++e)
        #pragma unroll
        for (int p2 = 0; p2 < 2; ++p2){
          const bf16x8 w0 = *(const bf16x8*)&s_Wc[(((e*2+0)*2+p2)*64 + lane)*8];
          const bf16x8 w1 = *(const bf16x8*)&s_Wc[(((e*2+1)*2+p2)*64 + lane)*8];
          ag[e][p2] = MFMA(xfH.v, w0, ag[e][p2]);
          ag[e][p2] = MFMA(xfL.v, w0, ag[e][p2]);
          ag[e][p2] = MFMA(hH.v,  w1, ag[e][p2]);
          ag[e][p2] = MFMA(hL.v,  w1, ag[e][p2]);
        }
      const bool snap = (t == len - 1);
      #pragma unroll
      for (int p2 = 0; p2 < 2; ++p2)
        #pragma unroll
        for (int j = 0; j < 4; ++j){
          const float pc = vvr[j][0]*ag[0][p2][j] + vvr[j][1]*ag[1][p2][j]
                         + vvr[j][2]*ag[2][p2][j] + vvr[j][3]*ag[3][p2][j]
                         + vvr[j][4]*ag[4][p2][j];
          const float cd = tanhfast(pc);
          const float hn = fmaf(uu[p2][j], cd - hr[p2][j], hr[p2][j]);
          const float hf = (m_cj[j] > 0.5f) ? hn : h[p2][j];
          h[p2][j] = hf;
          if (snap) outr[p2][j] = hf;
        }
    }

    // ---- write h to B0T[nxt] feature rows 32..63 ----
    {
      float h8[8] = {h[0][0],h[0][1],h[0][2],h[0][3],h[1][0],h[1][1],h[1][2],h[1][3]};
      bfu HH, HL;
      split8(h8, HH, HL);
      *(uint2*)&B0T[nxt][0][32 + l15][R + l16g*4] = make_uint2(HH.u[0], HH.u[1]);
      *(uint2*)&B0T[nxt][1][32 + l15][R + l16g*4] = make_uint2(HL.u[0], HL.u[1]);
      *(uint2*)&B0T[nxt][0][48 + l15][R + l16g*4] = make_uint2(HH.u[2], HH.u[3]);
      *(uint2*)&B0T[nxt][1][48 + l15][R + l16g*4] = make_uint2(HL.u[2], HL.u[3]);
    }

    // ---- next-step x / rar / tables into buf nxt ----
    if (more){
      const float rar_n = 0.5f * tanhfast(pa / (vto_own + 1.f));
      float xv[8];
      #pragma unroll
      for (int j = 0; j < 8; ++j){
        const int d = kgo + j;
        const float tearg = fmaf(pt, wpr[j], bpr[j]);
        const float te = (d == 0) ? tearg : __sinf(tearg);
        const float ve = fmaxf(fmaf(pd, wvr[j], bvr[j]), 0.f);
        xv[j] = (ve + te + embr[j]) * pm;
      }
      split8(xv, xfH, xfL);
      #pragma unroll
      for (int j = 0; j < 8; ++j){
        B0T[nxt][0][kgo + j][v_own] = xfH.s[j];
        B0T[nxt][1][kgo + j][v_own] = xfL.s[j];
      }
      if (l16g == 0){
        s_rar[nxt][v_own] = rar_n;
        s_m[nxt][v_own]   = pm;
      }
      rar_own = rar_n;
      m_own   = pm;
    }
    __syncthreads();
  }

  // ---- epilogue: feat -> 200-unit MLP -> 2 logits ----
  #pragma unroll
  for (int p2 = 0; p2 < 2; ++p2)
    #pragma unroll
    for (int j = 0; j < 4; ++j)
      s_outf[R + l16g*4 + j][p2*16 + l15] = outr[p2][j];
  __syncthreads();
  if (tid < VV){
    float s = 0.f;
    #pragma unroll
    for (int d = 0; d < DD; ++d) s += s_outf[tid][d];
    s_feat[tid] = s;
  } else if (tid < 2*VV){
    const int v = tid - VV;
    float se = bse[v];
    #pragma unroll
    for (int k = 0; k < 16; ++k) se = fmaf(Pstatic[b*16 + k], Wse[k*VV + v], se);
    s_feat[VV + v] = se;
  }
  __syncthreads();
  if (tid < 200){
    float a = bc1[tid];
    for (int k = 0; k < 128; ++k) a = fmaf(s_feat[k], Wc1[k*200 + tid], a);
    s_hid[tid] = fmaxf(a, 0.f);
  }
  __syncthreads();
  if (tid < 2){
    float a = bc2[tid];
    for (int k = 0; k < 200; ++k) a = fmaf(s_hid[k], Wc2[k*2 + tid], a);
    out[b*2 + tid] = a;
  }
}

// ---------------- launch ----------------

extern "C" void kernel_launch(void* const* d_in, const int* in_sizes, int n_in,
                              void* d_out, int out_size, void* d_ws, size_t ws_size,
                              hipStream_t stream) {
  (void)in_sizes; (void)n_in; (void)out_size; (void)ws_size;
  const float* P       = (const float*)d_in[0];
  const float* Pstatic = (const float*)d_in[1];
  const float* Pavg    = (const float*)d_in[2];
  const int*   Plen    = (const int*)  d_in[3];
  const float* Ptime   = (const float*)d_in[4];
  const float* Pplm    = (const float*)d_in[5];
  const float* w_val   = (const float*)d_in[6];
  const float* b_val   = (const float*)d_in[7];
  const float* w_per   = (const float*)d_in[8];
  const float* b_per   = (const float*)d_in[9];
  const float* w_lin   = (const float*)d_in[10];
  const float* b_lin   = (const float*)d_in[11];
  const float* emb1    = (const float*)d_in[12];
  const float* Ws1     = (const float*)d_in[13];
  const float* bs1     = (const float*)d_in[14];
  const float* Ws2     = (const float*)d_in[15];
  const float* bs2     = (const float*)d_in[16];
  const float* Wg1     = (const float*)d_in[17];
  const float* bg1     = (const float*)d_in[18];
  const float* Wg2     = (const float*)d_in[19];
  const float* bg2     = (const float*)d_in[20];
  const float* rarW    = (const float*)d_in[21];
  const float* Wu      = (const float*)d_in[22];
  const float* bu      = (const float*)d_in[23];
  const float* Wr      = (const float*)d_in[24];
  const float* br      = (const float*)d_in[25];
  const float* Wcand   = (const float*)d_in[26];
  const float* bcand   = (const float*)d_in[27];
  const float* Wse     = (const float*)d_in[28];
  const float* bse     = (const float*)d_in[29];
  const float* Wc1     = (const float*)d_in[30];
  const float* bc1     = (const float*)d_in[31];
  const float* Wc2     = (const float*)d_in[32];
  const float* bc2     = (const float*)d_in[33];

  float* ws = (float*)d_ws;
  float*          vv_ws   = ws;                 // 320 f
  float*          gn_ws   = ws + 320;           // 512 f
  float*          adjb_ws = ws + 832;           // 4096 f
  float*          vto_ws  = ws + 4928;          // 8192 f
  unsigned short* Bru_ws  = (unsigned short*)(ws + 13120);   // 20480 u16
  unsigned short* Bc_ws   = (unsigned short*)(ws + 23360);   // 10240 u16
  float*          sideRU_ws = ws + 28480;       // 640 f
  float*          sideC_ws  = ws + 29120;       // 320 f

  k_mlp  <<<64, 64, 0, stream>>>(Pplm, Ws1, bs1, Ws2, bs2, Wg1, bg1, Wg2, bg2, vv_ws, gn_ws);
  k_adj  <<<64, 64, 0, stream>>>(gn_ws, adjb_ws);
  k_vto  <<<(BB*VV + 255)/256, 256, 0, stream>>>(P, vto_ws);
  k_bpack<<<124, 256, 0, stream>>>(Wr, br, Wu, bu, Wcand, bcand, Bru_ws, Bc_ws, sideRU_ws, sideC_ws);

  tedgn_main<<<BB, 256, 0, stream>>>(P, Pstatic, Pavg, Plen, Ptime,
                                     w_val, b_val, w_per, b_per, w_lin, b_lin,
                                     emb1, rarW, Wse, bse, Wc1, bc1, Wc2, bc2,
                                     vv_ws, adjb_ws, vto_ws,
                                     Bru_ws, Bc_ws, sideRU_ws, sideC_ws,
                                     (float*)d_out);
}

// Round 9
// 586.201 us; speedup vs baseline: 13.5147x; 1.0635x over previous
//
#include <hip/hip_runtime.h>
#include <hip/hip_bf16.h>
#include <math.h>

#define BB 128
#define TT 128
#define VV 64
#define DD 32
#define NQ 5

typedef short bf16x8 __attribute__((ext_vector_type(8)));
typedef float f32x4 __attribute__((ext_vector_type(4)));

#define MFMA(a,b,c) __builtin_amdgcn_mfma_f32_16x16x32_bf16(a,b,c,0,0,0)

__device__ __forceinline__ float sigm(float x){ return 1.0f/(1.0f+__expf(-x)); }
__device__ __forceinline__ float tanhfast(float x){ return 2.0f/(1.0f+__expf(-2.0f*x)) - 1.0f; }
__device__ __forceinline__ unsigned short f2bf(float x){
  unsigned u = __float_as_uint(x);
  u += 0x7FFFu + ((u>>16)&1u);
  return (unsigned short)(u>>16);
}
__device__ __forceinline__ float bf2f(unsigned short h){
  return __uint_as_float(((unsigned)h)<<16);
}

union bfu { bf16x8 v; unsigned u[4]; unsigned short s[8]; };

// split 8 floats -> hi bf16x8 + lo bf16x8 (lo = rne(x - f32(hi))) via cvt_pk (RNE)
__device__ __forceinline__ void split8(const float* x, bfu& H, bfu& L){
  #pragma unroll
  for (int i = 0; i < 4; ++i){
    const float a = x[2*i], c = x[2*i+1];
    const __hip_bfloat162 hp = __float22bfloat162_rn(make_float2(a, c));
    unsigned hu; __builtin_memcpy(&hu, &hp, 4);
    H.u[i] = hu;
    const float ah = __uint_as_float(hu << 16);
    const float ch = __uint_as_float(hu & 0xFFFF0000u);
    const __hip_bfloat162 lp = __float22bfloat162_rn(make_float2(a - ah, c - ch));
    unsigned lu; __builtin_memcpy(&lu, &lp, 4);
    L.u[i] = lu;
  }
}

// split 4 floats -> 2x uint (4 bf16 hi) + 2x uint (4 bf16 lo)
__device__ __forceinline__ void split4(const float* x, unsigned* H, unsigned* L){
  #pragma unroll
  for (int i = 0; i < 2; ++i){
    const float a = x[2*i], c = x[2*i+1];
    const __hip_bfloat162 hp = __float22bfloat162_rn(make_float2(a, c));
    unsigned hu; __builtin_memcpy(&hu, &hp, 4);
    H[i] = hu;
    const float ah = __uint_as_float(hu << 16);
    const float ch = __uint_as_float(hu & 0xFFFF0000u);
    const __hip_bfloat162 lp = __float22bfloat162_rn(make_float2(a - ah, c - ch));
    unsigned lu; __builtin_memcpy(&lu, &lp, 4);
    L[i] = lu;
  }
}

// ---------------- precompute kernels ----------------

__global__ __launch_bounds__(64)
void k_mlp(const float* __restrict__ Pplm,
           const float* __restrict__ Ws1, const float* __restrict__ bs1,
           const float* __restrict__ Ws2, const float* __restrict__ bs2,
           const float* __restrict__ Wg1, const float* __restrict__ bg1,
           const float* __restrict__ Wg2, const float* __restrict__ bg2,
           float* __restrict__ vv_ws, float* __restrict__ gn_ws)
{
  __shared__ float sH[64], sG[64], sgv[8];
  const int v = blockIdx.x, j = threadIdx.x;
  float a = bs1[j], g = bg1[j];
  for (int k = 0; k < 768; ++k){
    const float p = Pplm[v*768 + k];
    a = fmaf(p, Ws1[k*64 + j], a);
    g = fmaf(p, Wg1[k*64 + j], g);
  }
  sH[j] = fmaxf(a, 0.f);
  sG[j] = fmaxf(g, 0.f);
  __syncthreads();
  if (j < 5){
    float acc = bs2[j];
    for (int k = 0; k < 64; ++k) acc = fmaf(sH[k], Ws2[k*5 + j], acc);
    vv_ws[v*5 + j] = acc;
  }
  if (j < 8){
    float acc = bg2[j];
    for (int k = 0; k < 64; ++k) acc = fmaf(sG[k], Wg2[k*8 + j], acc);
    sgv[j] = acc;
  }
  __syncthreads();
  if (j == 0){
    float n = 0.f;
    for (int e = 0; e < 8; ++e) n += sgv[e]*sgv[e];
    n = fmaxf(sqrtf(n), 1e-12f);
    for (int e = 0; e < 8; ++e) gn_ws[v*8 + e] = sgv[e]/n;
  }
}

__global__ __launch_bounds__(64)
void k_adj(const float* __restrict__ gn_ws, float* __restrict__ adj_ws)
{
  const int v = blockIdx.x, j = threadIdx.x;
  float sc = 0.f;
  #pragma unroll
  for (int e = 0; e < 8; ++e) sc += gn_ws[v*8+e]*gn_ws[j*8+e];
  float mx = sc;
  for (int off = 32; off > 0; off >>= 1) mx = fmaxf(mx, __shfl_xor(mx, off));
  const float ex = __expf(sc - mx);
  float sm = ex;
  for (int off = 32; off > 0; off >>= 1) sm += __shfl_xor(sm, off);
  adj_ws[v*64 + j] = ex / sm;
}

__global__ __launch_bounds__(256)
void k_vto(const float* __restrict__ P, float* __restrict__ vto_ws)
{
  const int idx = blockIdx.x*256 + threadIdx.x;
  if (idx >= BB*VV) return;
  const int b = idx/VV, v = idx%VV;
  float s = 0.f;
  for (int t = 0; t < TT; ++t) s += P[((size_t)(b*TT+t))*128 + 64 + v];
  vto_ws[idx] = s;
}

// pack gate weights into per-lane MFMA B-fragments (bf16) + paired side tables
// frag id f = ((e*2 + kt)*2 + p); element (f*64 + lane)*8 + j
// ALL gates use K-order [x(0..31) | h(0..31)] with rarity (orig k=32) as side:
//   k' = kt*32 + (lane>>4)*8 + j ; orig_k = (k'<32) ? k' : k'+1
// side tables: [e][o][2] pairs -> {rarity weight, bias}
__global__ __launch_bounds__(256)
void k_bpack(const float* __restrict__ Wr, const float* __restrict__ br,
             const float* __restrict__ Wu, const float* __restrict__ bu,
             const float* __restrict__ Wc, const float* __restrict__ bc,
             unsigned short* __restrict__ Bru, unsigned short* __restrict__ Bcn,
             float* __restrict__ sideRU, float* __restrict__ sideC)
{
  const int idx = blockIdx.x*256 + threadIdx.x;
  if (idx < 20480){
    const int f = idx >> 9, rem = idx & 511, l = rem >> 3, j = rem & 7;
    const int p = f & 1, kt = (f>>1)&1, e = f>>2;
    const int kp = kt*32 + (l>>4)*8 + j;
    const int k = (kp < 32) ? kp : kp + 1;
    const int o = p*16 + (l&15);
    const int q = (e < 5) ? e : e - 5;
    const float* W = (e < 5) ? Wr : Wu;
    Bru[idx] = f2bf(W[(q*65 + k)*32 + o]);
  } else if (idx < 30720){
    const int i2 = idx - 20480;
    const int f = i2 >> 9, rem = i2 & 511, l = rem >> 3, j = rem & 7;
    const int p = f & 1, kt = (f>>1)&1, e = f>>2;
    const int kp = kt*32 + (l>>4)*8 + j;
    const int k = (kp < 32) ? kp : kp + 1;
    const int o = p*16 + (l&15);
    Bcn[i2] = f2bf(Wc[(e*65 + k)*32 + o]);
  } else if (idx < 31360){
    const int i3 = idx - 30720;            // [e:10][o:32][s:2] pairs
    const int e = i3 >> 6, rem = i3 & 63, o = rem >> 1, s = rem & 1;
    const int q = (e < 5) ? e : e - 5;
    float v;
    if (s == 0) v = (e < 5) ? Wr[(q*65 + 32)*32 + o] : Wu[(q*65 + 32)*32 + o]; // rarity weight
    else        v = (e < 5) ? br[q*32 + o] : bu[q*32 + o];
    sideRU[i3] = v;
  } else if (idx < 31680){
    const int i4 = idx - 31360;            // [e:5][o:32][s:2] pairs
    const int e = i4 >> 6, rem = i4 & 63, o = rem >> 1, s = rem & 1;
    sideC[i4] = s ? bc[e*32 + o] : Wc[(e*65 + 32)*32 + o];   // s=0: rarity weight
  }
}

// ---------------- main recurrent kernel: 1 block (512 thr / 8 waves) per batch ----------------
// wave (mq, ph): mq = wid>>1 owns rows R..R+15; ph = wid&1 owns o-half ph*16..+15.
// 3 barriers/step: comb->gates (A1f), r/u->cand (hrF), tail->next step (B0T).

__global__ __launch_bounds__(512, 1)
void tedgn_main(const float* __restrict__ P, const float* __restrict__ Pstatic,
                const float* __restrict__ Pavg, const int* __restrict__ Plen,
                const float* __restrict__ Ptime,
                const float* __restrict__ w_val, const float* __restrict__ b_val,
                const float* __restrict__ w_per, const float* __restrict__ b_per,
                const float* __restrict__ w_lin, const float* __restrict__ b_lin,
                const float* __restrict__ emb1, const float* __restrict__ rarW,
                const float* __restrict__ Wse, const float* __restrict__ bse,
                const float* __restrict__ Wc1, const float* __restrict__ bc1,
                const float* __restrict__ Wc2, const float* __restrict__ bc2,
                const float* __restrict__ vv_ws, const float* __restrict__ adjb_ws,
                const float* __restrict__ vto_ws,
                const unsigned short* __restrict__ Bru_ws,
                const unsigned short* __restrict__ Bc_ws,
                const float* __restrict__ sideRU_ws, const float* __restrict__ sideC_ws,
                float* __restrict__ out)
{
  // XH^T double-buffered: [buf][hi/lo][feature 0..63 = x(32)|h(32)][v, pad 72]
  __shared__ __align__(16) unsigned short B0T[2][2][64][72];
  __shared__ __align__(16) unsigned short s_Wru[20480];   // gate weight B-fragments
  __shared__ __align__(16) unsigned short s_Wc[10240];
  __shared__ __align__(16) float A1f[4][16][68];   // per-mq comb rows (f32); col 64 = comb_rar
  __shared__ __align__(16) float hrF[4][16][36];   // per-mq h_r rows (f32)
  __shared__ __align__(16) float s_rar[2][64];
  __shared__ __align__(16) float s_m[2][64];
  __shared__ float s_sru[640], s_scd[320];
  __shared__ float s_outf[64][33];
  __shared__ float s_feat[128], s_hid[200];

  const int tid  = threadIdx.x;
  const int lane = tid & 63;
  const int wid  = tid >> 6;      // 8 waves
  const int mq   = wid >> 1;      // row quarter
  const int ph   = wid & 1;       // o-half
  const int l15  = lane & 15;
  const int l16g = lane >> 4;
  const int kgo  = l16g * 8;
  const int R    = mq * 16;
  const int v_own = R + l15;
  const int oo   = ph*16 + l15;
  const int b    = blockIdx.x;
  const int len  = Plen[b];

  // LDS fills: side tables + weight fragments
  for (int i = tid; i < 640; i += 512) s_sru[i] = sideRU_ws[i];
  for (int i = tid; i < 320; i += 512) s_scd[i] = sideC_ws[i];
  {
    const uint4* src1 = (const uint4*)Bru_ws;
    uint4* dst1 = (uint4*)s_Wru;
    for (int i = tid; i < 2560; i += 512) dst1[i] = src1[i];
    const uint4* src2 = (const uint4*)Bc_ws;
    uint4* dst2 = (uint4*)s_Wc;
    for (int i = tid; i < 1280; i += 512) dst2[i] = src2[i];
  }

  // per-lane constants (keyed on v_own; duplicated across ph waves)
  float adjb_r[2][8], rarW_r[2][8];
  #pragma unroll
  for (int kt = 0; kt < 2; ++kt)
    #pragma unroll
    for (int j = 0; j < 8; ++j){
      adjb_r[kt][j] = adjb_ws[v_own*64 + kt*32 + kgo + j];
      rarW_r[kt][j] = rarW   [v_own*64 + kt*32 + kgo + j];
    }
  float embr[8], wvr[8], bvr[8], wpr[8], bpr[8];
  #pragma unroll
  for (int j = 0; j < 8; ++j){
    const int d = kgo + j;
    embr[j] = emb1[v_own*DD + d];
    wvr[j]  = w_val[d];
    bvr[j]  = b_val[d];
    wpr[j]  = (d == 0) ? w_lin[0] : w_per[d-1];
    bpr[j]  = (d == 0) ? b_lin[0] : b_per[d-1];
  }
  float vvr[4][NQ];
  #pragma unroll
  for (int j = 0; j < 4; ++j)
    #pragma unroll
    for (int q = 0; q < NQ; ++q)
      vvr[j][q] = vv_ws[(R + l16g*4 + j)*NQ + q];
  const float vto_own = vto_ws[b*VV + v_own];

  float h[4]    = {0.f,0.f,0.f,0.f};     // rows R+l16g*4+j, col oo
  float outr[4] = {0.f,0.f,0.f,0.f};
  bfu xfH, xfL;
  float rar_own, m_own;

  // ---- prologue: build step-0 state into buf 0 ----
  {
    const float pd = P[(size_t)(b*TT)*128 + v_own];
    const float pm = P[(size_t)(b*TT)*128 + 64 + v_own];
    const float pa = Pavg[(size_t)(b*TT)*VV + v_own];
    const float pt = Ptime[b*TT];
    const float rar_n = 0.5f * tanhfast(pa / (vto_own + 1.f));
    float xv[8];
    #pragma unroll
    for (int j = 0; j < 8; ++j){
      const int d = kgo + j;
      const float tearg = fmaf(pt, wpr[j], bpr[j]);
      const float te = (d == 0) ? tearg : __sinf(tearg);
      const float ve = fmaxf(fmaf(pd, wvr[j], bvr[j]), 0.f);
      xv[j] = (ve + te + embr[j]) * pm;
    }
    split8(xv, xfH, xfL);
    if (ph == 0){
      #pragma unroll
      for (int j = 0; j < 8; ++j){
        B0T[0][0][kgo + j][v_own] = xfH.s[j];
        B0T[0][1][kgo + j][v_own] = xfL.s[j];
      }
      // zero h rows 32..47
      *(uint2*)&B0T[0][0][32 + l15][R + l16g*4] = make_uint2(0u, 0u);
      *(uint2*)&B0T[0][1][32 + l15][R + l16g*4] = make_uint2(0u, 0u);
      if (l16g == 0){
        s_rar[0][v_own] = rar_n;
        s_m[0][v_own]   = pm;
      }
    } else {
      // zero h rows 48..63
      *(uint2*)&B0T[0][0][48 + l15][R + l16g*4] = make_uint2(0u, 0u);
      *(uint2*)&B0T[0][1][48 + l15][R + l16g*4] = make_uint2(0u, 0u);
    }
    rar_own = rar_n;
    m_own   = pm;
  }
  __syncthreads();

  #pragma clang loop unroll(disable)
  for (int t = 0; t < TT; ++t){
    const int cur = t & 1, nxt = cur ^ 1;

    // prefetch t+1 (consumed in tail)
    float pd = 0.f, pm = 0.f, pa = 0.f, pt = 0.f;
    const bool more = (t + 1 < TT);
    if (more){
      pd = P[(size_t)(b*TT + t + 1)*128 + v_own];
      pm = P[(size_t)(b*TT + t + 1)*128 + 64 + v_own];
      pa = Pavg[(size_t)(b*TT + t + 1)*VV + v_own];
      pt = Ptime[b*TT + t + 1];
    }

    // ---- Phase A: adj A-fragments + comb_rar + comb (2 N-tiles per wave) ----
    {
      bfu aAh[2], aAl[2];
      float crar = 0.f;
      #pragma unroll
      for (int kt = 0; kt < 2; ++kt){
        const float4 r0 = *(const float4*)&s_rar[cur][kt*32 + kgo];
        const float4 r1 = *(const float4*)&s_rar[cur][kt*32 + kgo + 4];
        const float4 m0 = *(const float4*)&s_m[cur][kt*32 + kgo];
        const float4 m1 = *(const float4*)&s_m[cur][kt*32 + kgo + 4];
        const float rj[8] = {r0.x,r0.y,r0.z,r0.w,r1.x,r1.y,r1.z,r1.w};
        const float mj[8] = {m0.x,m0.y,m0.z,m0.w,m1.x,m1.y,m1.z,m1.w};
        float av[8];
        #pragma unroll
        for (int j = 0; j < 8; ++j){
          const int k = kt*32 + kgo + j;
          const float e1 = fmaf(-rarW_r[kt][j], fabsf(rar_own - rj[j]), 1.0f);
          const float a  = adjb_r[kt][j] * e1 * (m_own * mj[j]);
          av[j] = (k == v_own) ? 1.0f : a;
          crar = fmaf(av[j], rj[j], crar);
        }
        split8(av, aAh[kt], aAl[kt]);
      }
      crar += __shfl_xor(crar, 16);
      crar += __shfl_xor(crar, 32);
      if (ph == 0 && l16g == 0) A1f[mq][l15][64] = crar;

      #pragma unroll
      for (int ni = 0; ni < 2; ++ni){
        const int n = 2*ph + ni;
        f32x4 acc = {0.f,0.f,0.f,0.f};
        #pragma unroll
        for (int kt = 0; kt < 2; ++kt){
          const bf16x8 bh = *(const bf16x8*)&B0T[cur][0][n*16 + l15][kt*32 + kgo];
          const bf16x8 bl = *(const bf16x8*)&B0T[cur][1][n*16 + l15][kt*32 + kgo];
          acc = MFMA(aAh[kt].v, bh, acc);
          acc = MFMA(aAl[kt].v, bh, acc);
          acc = MFMA(aAh[kt].v, bl, acc);
        }
        const int col = n*16 + l15;
        #pragma unroll
        for (int j = 0; j < 4; ++j) A1f[mq][l16g*4 + j][col] = acc[j];
      }
    }
    __syncthreads();   // barrier 1: A1f complete

    // ---- Phase B: gate A-fragments + r/u gates (own o-half only) ----
    float hr[4], uu[4];
    {
      bfu aH[2], aL[2];
      #pragma unroll
      for (int kt = 0; kt < 2; ++kt){
        float xv[8];
        *(float4*)&xv[0] = *(const float4*)&A1f[mq][l15][kt*32 + kgo];
        *(float4*)&xv[4] = *(const float4*)&A1f[mq][l15][kt*32 + kgo + 4];
        split8(xv, aH[kt], aL[kt]);
      }
      float a64f[4];
      #pragma unroll
      for (int j = 0; j < 4; ++j) a64f[j] = A1f[mq][l16g*4 + j][64];

      f32x4 ag[10];
      #pragma unroll
      for (int e = 0; e < 10; ++e){
        const float2 wb = *(const float2*)&s_sru[e*64 + oo*2];
        #pragma unroll
        for (int j = 0; j < 4; ++j) ag[e][j] = fmaf(a64f[j], wb.x, wb.y);
      }
      #pragma unroll
      for (int e = 0; e < 10; ++e){
        const bf16x8 w0 = *(const bf16x8*)&s_Wru[(((e*2+0)*2+ph)*64 + lane)*8];
        const bf16x8 w1 = *(const bf16x8*)&s_Wru[(((e*2+1)*2+ph)*64 + lane)*8];
        ag[e] = MFMA(aH[0].v, w0, ag[e]);
        ag[e] = MFMA(aL[0].v, w0, ag[e]);
        ag[e] = MFMA(aH[1].v, w1, ag[e]);
        ag[e] = MFMA(aL[1].v, w1, ag[e]);
      }
      #pragma unroll
      for (int j = 0; j < 4; ++j){
        const float pr = vvr[j][0]*ag[0][j] + vvr[j][1]*ag[1][j]
                       + vvr[j][2]*ag[2][j] + vvr[j][3]*ag[3][j]
                       + vvr[j][4]*ag[4][j];
        hr[j] = sigm(pr) * h[j];
        hrF[mq][l16g*4 + j][oo] = hr[j];
      }
      #pragma unroll
      for (int j = 0; j < 4; ++j){
        const float pu = vvr[j][0]*ag[5][j] + vvr[j][1]*ag[6][j]
                       + vvr[j][2]*ag[7][j] + vvr[j][3]*ag[8][j]
                       + vvr[j][4]*ag[9][j];
        uu[j] = sigm(pu);
      }
    }
    __syncthreads();   // barrier 2: hrF complete

    // ---- Phase C: cand + GRU update + B0T[nxt] writes + next-step prep ----
    {
      bfu hH, hL;
      {
        float hv[8];
        *(float4*)&hv[0] = *(const float4*)&hrF[mq][l15][kgo];
        *(float4*)&hv[4] = *(const float4*)&hrF[mq][l15][kgo + 4];
        split8(hv, hH, hL);
      }
      float rar_cj[4], m_cj[4];
      #pragma unroll
      for (int j = 0; j < 4; ++j){
        rar_cj[j] = s_rar[cur][R + l16g*4 + j];
        m_cj[j]   = s_m[cur][R + l16g*4 + j];
      }
      f32x4 ag[5];
      #pragma unroll
      for (int e = 0; e < 5; ++e){
        const float2 wb = *(const float2*)&s_scd[e*64 + oo*2];
        #pragma unroll
        for (int j = 0; j < 4; ++j) ag[e][j] = fmaf(rar_cj[j], wb.x, wb.y);
      }
      #pragma unroll
      for (int e = 0; e < 5; ++e){
        const bf16x8 w0 = *(const bf16x8*)&s_Wc[(((e*2+0)*2+ph)*64 + lane)*8];
        const bf16x8 w1 = *(const bf16x8*)&s_Wc[(((e*2+1)*2+ph)*64 + lane)*8];
        ag[e] = MFMA(xfH.v, w0, ag[e]);
        ag[e] = MFMA(xfL.v, w0, ag[e]);
        ag[e] = MFMA(hH.v,  w1, ag[e]);
        ag[e] = MFMA(hL.v,  w1, ag[e]);
      }
      const bool snap = (t == len - 1);
      #pragma unroll
      for (int j = 0; j < 4; ++j){
        const float pc = vvr[j][0]*ag[0][j] + vvr[j][1]*ag[1][j]
                       + vvr[j][2]*ag[2][j] + vvr[j][3]*ag[3][j]
                       + vvr[j][4]*ag[4][j];
        const float cd = tanhfast(pc);
        const float hn = fmaf(uu[j], cd - hr[j], hr[j]);
        const float hf = (m_cj[j] > 0.5f) ? hn : h[j];
        h[j] = hf;
        if (snap) outr[j] = hf;
      }
      // write h to B0T[nxt] row 32+oo, cols R+l16g*4..+3
      {
        unsigned H2[2], L2[2];
        split4(h, H2, L2);
        *(uint2*)&B0T[nxt][0][32 + oo][R + l16g*4] = make_uint2(H2[0], H2[1]);
        *(uint2*)&B0T[nxt][1][32 + oo][R + l16g*4] = make_uint2(L2[0], L2[1]);
      }
      // next-step x / rar / m into buf nxt
      if (more){
        const float rar_n = 0.5f * tanhfast(pa / (vto_own + 1.f));
        float xv[8];
        #pragma unroll
        for (int j = 0; j < 8; ++j){
          const int d = kgo + j;
          const float tearg = fmaf(pt, wpr[j], bpr[j]);
          const float te = (d == 0) ? tearg : __sinf(tearg);
          const float ve = fmaxf(fmaf(pd, wvr[j], bvr[j]), 0.f);
          xv[j] = (ve + te + embr[j]) * pm;
        }
        split8(xv, xfH, xfL);
        if (ph == 0){
          #pragma unroll
          for (int j = 0; j < 8; ++j){
            B0T[nxt][0][kgo + j][v_own] = xfH.s[j];
            B0T[nxt][1][kgo + j][v_own] = xfL.s[j];
          }
          if (l16g == 0){
            s_rar[nxt][v_own] = rar_n;
            s_m[nxt][v_own]   = pm;
          }
        }
        rar_own = rar_n;
        m_own   = pm;
      }
    }
    __syncthreads();   // barrier 3: B0T[nxt]/rar/m complete
  }

  // ---- epilogue: feat -> 200-unit MLP -> 2 logits ----
  #pragma unroll
  for (int j = 0; j < 4; ++j)
    s_outf[R + l16g*4 + j][oo] = outr[j];
  __syncthreads();
  if (tid < VV){
    float s = 0.f;
    #pragma unroll
    for (int d = 0; d < DD; ++d) s += s_outf[tid][d];
    s_feat[tid] = s;
  } else if (tid < 2*VV){
    const int v = tid - VV;
    float se = bse[v];
    #pragma unroll
    for (int k = 0; k < 16; ++k) se = fmaf(Pstatic[b*16 + k], Wse[k*VV + v], se);
    s_feat[VV + v] = se;
  }
  __syncthreads();
  if (tid < 200){
    float a = bc1[tid];
    for (int k = 0; k < 128; ++k) a = fmaf(s_feat[k], Wc1[k*200 + tid], a);
    s_hid[tid] = fmaxf(a, 0.f);
  }
  __syncthreads();
  if (tid < 2){
    float a = bc2[tid];
    for (int k = 0; k < 200; ++k) a = fmaf(s_hid[k], Wc2[k*2 + tid], a);
    out[b*2 + tid] = a;
  }
}

// ---------------- launch ----------------

extern "C" void kernel_launch(void* const* d_in, const int* in_sizes, int n_in,
                              void* d_out, int out_size, void* d_ws, size_t ws_size,
                              hipStream_t stream) {
  (void)in_sizes; (void)n_in; (void)out_size; (void)ws_size;
  const float* P       = (const float*)d_in[0];
  const float* Pstatic = (const float*)d_in[1];
  const float* Pavg    = (const float*)d_in[2];
  const int*   Plen    = (const int*)  d_in[3];
  const float* Ptime   = (const float*)d_in[4];
  const float* Pplm    = (const float*)d_in[5];
  const float* w_val   = (const float*)d_in[6];
  const float* b_val   = (const float*)d_in[7];
  const float* w_per   = (const float*)d_in[8];
  const float* b_per   = (const float*)d_in[9];
  const float* w_lin   = (const float*)d_in[10];
  const float* b_lin   = (const float*)d_in[11];
  const float* emb1    = (const float*)d_in[12];
  const float* Ws1     = (const float*)d_in[13];
  const float* bs1     = (const float*)d_in[14];
  const float* Ws2     = (const float*)d_in[15];
  const float* bs2     = (const float*)d_in[16];
  const float* Wg1     = (const float*)d_in[17];
  const float* bg1     = (const float*)d_in[18];
  const float* Wg2     = (const float*)d_in[19];
  const float* bg2     = (const float*)d_in[20];
  const float* rarW    = (const float*)d_in[21];
  const float* Wu      = (const float*)d_in[22];
  const float* bu      = (const float*)d_in[23];
  const float* Wr      = (const float*)d_in[24];
  const float* br      = (const float*)d_in[25];
  const float* Wcand   = (const float*)d_in[26];
  const float* bcand   = (const float*)d_in[27];
  const float* Wse     = (const float*)d_in[28];
  const float* bse     = (const float*)d_in[29];
  const float* Wc1     = (const float*)d_in[30];
  const float* bc1     = (const float*)d_in[31];
  const float* Wc2     = (const float*)d_in[32];
  const float* bc2     = (const float*)d_in[33];

  float* ws = (float*)d_ws;
  float*          vv_ws   = ws;                 // 320 f
  float*          gn_ws   = ws + 320;           // 512 f
  float*          adjb_ws = ws + 832;           // 4096 f
  float*          vto_ws  = ws + 4928;          // 8192 f
  unsigned short* Bru_ws  = (unsigned short*)(ws + 13120);   // 20480 u16
  unsigned short* Bc_ws   = (unsigned short*)(ws + 23360);   // 10240 u16
  float*          sideRU_ws = ws + 28480;       // 640 f
  float*          sideC_ws  = ws + 29120;       // 320 f

  k_mlp  <<<64, 64, 0, stream>>>(Pplm, Ws1, bs1, Ws2, bs2, Wg1, bg1, Wg2, bg2, vv_ws, gn_ws);
  k_adj  <<<64, 64, 0, stream>>>(gn_ws, adjb_ws);
  k_vto  <<<(BB*VV + 255)/256, 256, 0, stream>>>(P, vto_ws);
  k_bpack<<<124, 256, 0, stream>>>(Wr, br, Wu, bu, Wcand, bcand, Bru_ws, Bc_ws, sideRU_ws, sideC_ws);

  tedgn_main<<<BB, 512, 0, stream>>>(P, Pstatic, Pavg, Plen, Ptime,
                                     w_val, b_val, w_per, b_per, w_lin, b_lin,
                                     emb1, rarW, Wse, bse, Wc1, bc1, Wc2, bc2,
                                     vv_ws, adjb_ws, vto_ws,
                                     Bru_ws, Bc_ws, sideRU_ws, sideC_ws,
                                     (float*)d_out);
}